// Round 8
// baseline (516.180 us; speedup 1.0000x reference)
//
#include <hip/hip_runtime.h>
#include <stdint.h>

typedef __attribute__((ext_vector_type(8))) __bf16 bf16x8;
typedef __attribute__((ext_vector_type(4))) float f32x4;
typedef __attribute__((ext_vector_type(4))) unsigned int uint4v;

__device__ __forceinline__ float bf2f(unsigned short u){
  unsigned int x = ((unsigned int)u) << 16;
  return __builtin_bit_cast(float, x);
}
__device__ __forceinline__ unsigned short f2bf(float f){
  unsigned int x = __builtin_bit_cast(unsigned int, f);
  x += 0x7FFFu + ((x >> 16) & 1u);
  return (unsigned short)(x >> 16);
}

#define OUT_F32 0
#define OUT_BF16 1
#define OUT_SPLIT3 2
#define OUT_FLAG 3
#define OUT_PART 4
#define OUT_PARTH 5
#define BIAS_NONE 0
#define BIAS_ROW 1
#define BIAS_COL 2

// C(MxN) = A(MxK) * Bt(NxK)^T ; M mult of 256, N mult of 128, kchunk mult of 32.
// 256x128 block tile, 4 waves (2x2), wave tile 128x64, acc 8x4, 16x16x32 MFMA.
// Rationale (R7 counters): MfmaUtil pinned ~23% with VALU 13%, HBM 28% =>
// LDS-traffic-per-FLOP limited; 256-tile halves LDS bytes/FLOP vs 128-tile.
// Register staging + double-buffered LDS (48KB), one barrier per K-step.
// LDS: row r at byte r*64; 16B-chunk p of row r holds k-chunk (p ^ ((r>>1)&3)).
template<int OM, int BM>
__global__ __launch_bounds__(256)
void gemm_bt(const unsigned short* __restrict__ A, int lda,
             const unsigned short* __restrict__ Bt, int ldb,
             int kchunk, void* __restrict__ Out, int ldo,
             const float* __restrict__ bias,
             int dupOff, int loOff,
             const unsigned int* __restrict__ flagPtr, size_t outOff,
             size_t zStride)
{
  __shared__ uint4v AsmBuf[2048];   // 2 x 16KB (256 rows x 64B)
  __shared__ uint4v BsmBuf[1024];   // 2 x 8KB  (128 rows x 64B)
  char* Asm = (char*)AsmBuf;
  char* Bsm = (char*)BsmBuf;

  const unsigned int fl = (OM == OUT_FLAG) ? flagPtr[0] : 0u;

  const int tid  = threadIdx.x;
  const int lane = tid & 63;
  const int wave = tid >> 6;
  const int wy = wave >> 1, wx = wave & 1;
  const int lm = lane & 15, quad = lane >> 4;
  const int tileM = blockIdx.y * 256;
  const int tileN = blockIdx.x * 128;
  const int z = blockIdx.z;

  A  += (size_t)z * kchunk;
  Bt += (size_t)z * kchunk;

  // staging: thread handles A rows sr+{0,64,128,192}, B rows sr+{0,64}; chunk sc
  const int sr = tid >> 2, sc = tid & 3;
  size_t gA[4]; int lA[4];
  size_t gB[2]; int lB[2];
#pragma unroll
  for (int i = 0; i < 4; ++i){
    const int r = sr + 64*i;
    gA[i] = (size_t)(tileM + r)*lda + ((sc ^ ((r >> 1) & 3)) << 3);
    lA[i] = r*64 + sc*16;
  }
#pragma unroll
  for (int i = 0; i < 2; ++i){
    const int r = sr + 64*i;
    gB[i] = (size_t)(tileN + r)*ldb + ((sc ^ ((r >> 1) & 3)) << 3);
    lB[i] = r*64 + sc*16;
  }

  int aOff[8], bOff[4];
#pragma unroll
  for (int t = 0; t < 8; ++t){
    const int ra = wy*128 + t*16 + lm;
    aOff[t] = ra*64 + ((quad ^ ((ra >> 1) & 3)) << 4);
  }
#pragma unroll
  for (int t = 0; t < 4; ++t){
    const int rb = wx*64 + t*16 + lm;
    bOff[t] = rb*64 + ((quad ^ ((rb >> 1) & 3)) << 4);
  }

  f32x4 acc[8][4] = {};

  const int ksteps = kchunk >> 5;
  // prologue: prefetch k-step 0 into registers
  uint4v av[4], bv[2];
#pragma unroll
  for (int i = 0; i < 4; ++i) av[i] = *(const uint4v*)(A + gA[i]);
#pragma unroll
  for (int i = 0; i < 2; ++i) bv[i] = *(const uint4v*)(Bt + gB[i]);

  for (int kt = 0; kt < ksteps; ++kt){
    char* As = Asm + (kt & 1)*16384;
    char* Bs = Bsm + (kt & 1)*8192;
#pragma unroll
    for (int i = 0; i < 4; ++i) *(uint4v*)(As + lA[i]) = av[i];
#pragma unroll
    for (int i = 0; i < 2; ++i) *(uint4v*)(Bs + lB[i]) = bv[i];
    __syncthreads();
    if (kt + 1 < ksteps){
      const unsigned short* Ak = A + (kt + 1)*32;
      const unsigned short* Bk = Bt + (kt + 1)*32;
#pragma unroll
      for (int i = 0; i < 4; ++i) av[i] = *(const uint4v*)(Ak + gA[i]);
#pragma unroll
      for (int i = 0; i < 2; ++i) bv[i] = *(const uint4v*)(Bk + gB[i]);
    }
    bf16x8 af[8], bfr[4];
#pragma unroll
    for (int t = 0; t < 8; ++t)
      af[t] = __builtin_bit_cast(bf16x8, *(const uint4v*)(As + aOff[t]));
#pragma unroll
    for (int t = 0; t < 4; ++t)
      bfr[t] = __builtin_bit_cast(bf16x8, *(const uint4v*)(Bs + bOff[t]));
#pragma unroll
    for (int tm = 0; tm < 8; ++tm)
#pragma unroll
      for (int tn = 0; tn < 4; ++tn)
        acc[tm][tn] = __builtin_amdgcn_mfma_f32_16x16x32_bf16(af[tm], bfr[tn], acc[tm][tn], 0, 0, 0);
  }

  // D row = quad*4 + reg, col = lane&15
#pragma unroll
  for (int tm = 0; tm < 8; ++tm){
    const int rowb = tileM + wy*128 + tm*16 + quad*4;
#pragma unroll
    for (int tn = 0; tn < 4; ++tn){
      const int col = tileN + wx*64 + tn*16 + lm;
      float bcv = 0.f;
      if (BM == BIAS_COL) bcv = bias[col];
#pragma unroll
      for (int r = 0; r < 4; ++r){
        float v = acc[tm][tn][r];
        const int row = rowb + r;
        if (BM == BIAS_ROW) v += bias[row];
        if (BM == BIAS_COL) v += bcv;
        const size_t idx = (size_t)row*ldo + col;
        if (OM == OUT_F32){
          ((float*)Out)[idx] = v;
        } else if (OM == OUT_BF16){
          ((unsigned short*)Out)[idx] = f2bf(v);
        } else if (OM == OUT_SPLIT3){
          unsigned short hi = f2bf(v);
          unsigned short lo = f2bf(v - bf2f(hi));
          unsigned short* O = (unsigned short*)Out;
          O[idx] = hi; O[idx + dupOff] = hi; O[idx + loOff] = lo;
        } else if (OM == OUT_PART){
          ((float*)Out)[(size_t)z*zStride + idx] = v;
        } else if (OM == OUT_PARTH){
          ((unsigned short*)Out)[(size_t)z*zStride + idx] = f2bf(v);
        } else { // OUT_FLAG
          if (fl) ((float*)Out)[outOff + idx] = v;
          else    ((unsigned short*)Out)[outOff + idx] = f2bf(v);
        }
      }
    }
  }
}

// sum S partial slices (flat [S][rows*cols]) -> epilogue.
// CSH = log2(cols). HALFP: bf16 partials. i = bid*256+tid; row=i>>CSH, col=i&mask.
template<int S, int OM, int BM, int CSH, bool HALFP>
__global__ __launch_bounds__(256)
void reduce_part(const void* __restrict__ part, size_t zStride,
                 const float* __restrict__ bias,
                 void* __restrict__ Out, int ldo,
                 int dupOff, int loOff,
                 const unsigned int* __restrict__ flagPtr, size_t outOff)
{
  const size_t i = (size_t)blockIdx.x*256 + threadIdx.x;
  const int row = (int)(i >> CSH);
  const int col = (int)(i & ((1u << CSH) - 1u));
  float v = 0.f;
#pragma unroll
  for (int s = 0; s < S; ++s){
    if (HALFP) v += bf2f(((const unsigned short*)part)[(size_t)s*zStride + i]);
    else       v += ((const float*)part)[(size_t)s*zStride + i];
  }
  if (BM == BIAS_ROW) v += bias[row];
  if (BM == BIAS_COL) v += bias[col];
  const size_t o = (size_t)row*ldo + col;
  if (OM == OUT_SPLIT3){
    unsigned short hi = f2bf(v);
    unsigned short lo = f2bf(v - bf2f(hi));
    unsigned short* O = (unsigned short*)Out;
    O[o] = hi; O[o + dupOff] = hi; O[o + loOff] = lo;
  } else if (OM == OUT_BF16){
    ((unsigned short*)Out)[o] = f2bf(v);
  } else { // OUT_FLAG
    if (flagPtr[0]) ((float*)Out)[outOff + o] = v;
    else            ((unsigned short*)Out)[outOff + o] = f2bf(v);
  }
}

// dtype vote + scalar/bias canonicalization (f32 canon)
__global__ __launch_bounds__(256)
void detect_prep(const void* __restrict__ content,
                 const void* tb, const void* pb, const void* gb, const void* wb,
                 const void* sc,
                 unsigned int* __restrict__ flag, float* __restrict__ scale_c,
                 float* tb_c, float* pb_c, float* gb_c, float* wb_c)
{
  __shared__ int cnt;
  __shared__ unsigned int flg;
  const int tid = threadIdx.x;
  if (tid == 0) cnt = 0;
  __syncthreads();
  unsigned int w = ((const unsigned int*)content)[tid];
  int e = (w >> 23) & 0xFF;
  if (e >= 0x70 && e <= 0x8F) atomicAdd(&cnt, 1);
  __syncthreads();
  if (tid == 0){ flg = (cnt >= 128) ? 1u : 0u; flag[0] = flg; }
  __syncthreads();
  const unsigned int f = flg;
  auto rd = [&](const void* p, int i)->float{
    return f ? ((const float*)p)[i] : bf2f(((const unsigned short*)p)[i]);
  };
  if (tid < 9) scale_c[tid] = rd(sc, tid);
  tb_c[tid] = rd(tb, tid);
  pb_c[tid] = rd(pb, tid);
  gb_c[tid] = rd(gb, tid);
  wb_c[tid] = rd(wb, tid);
  wb_c[tid + 256] = rd(wb, tid + 256);
}

// canonicalize weights: theta/phi -> wdup rows [whi(512)|wlo(512)|whi(512)],
// g_w -> gwc bf16, W_w -> wwc bf16
__global__ __launch_bounds__(256)
void conv_weights(const void* tw, const void* pw, const void* gw, const void* www,
                  const unsigned int* __restrict__ flagPtr,
                  unsigned short* __restrict__ wdup,
                  unsigned short* __restrict__ gwc,
                  unsigned short* __restrict__ wwc)
{
  const unsigned int fl = flagPtr[0];
  const int sec = blockIdx.y;
  const int idx = blockIdx.x*256 + threadIdx.x;
  auto rd = [&](const void* p, int i)->float{
    return fl ? ((const float*)p)[i] : bf2f(((const unsigned short*)p)[i]);
  };
  if (sec < 2){
    const void* w = sec ? pw : tw;
    const int o = idx >> 9, c = idx & 511;
    float v = rd(w, o*512 + c);
    unsigned short hi = f2bf(v);
    unsigned short lo = f2bf(v - bf2f(hi));
    unsigned short* base = wdup + (size_t)sec*256*1536 + o*1536;
    base[c] = hi; base[512 + c] = lo; base[1024 + c] = hi;
  } else if (sec == 2){
    const int o = idx >> 9, c = idx & 511;
    gwc[o*512 + c] = f2bf(rd(gw, o*512 + c));
  } else {
    const int o = idx >> 8, c = idx & 255;
    wwc[o*256 + c] = f2bf(rd(www, o*256 + c));
  }
}

// per-(b,c) mean / invstd over 4096 spatial elems (unbiased var)
__global__ __launch_bounds__(256)
void stats_kernel(const void* __restrict__ X, const unsigned int* __restrict__ flagPtr,
                  float* __restrict__ stats)
{
  const unsigned int fl = flagPtr[0];
  const int bc = blockIdx.x;
  const int tid = threadIdx.x;
  float s = 0.f, q = 0.f;
  if (fl){
    const f32x4* row = (const f32x4*)((const float*)X + (size_t)bc*4096);
#pragma unroll
    for (int i = 0; i < 4; ++i){
      f32x4 v = row[tid + i*256];
#pragma unroll
      for (int j = 0; j < 4; ++j){ s += v[j]; q += v[j]*v[j]; }
    }
  } else {
    const uint4v* row = (const uint4v*)((const unsigned short*)X + (size_t)bc*4096);
#pragma unroll
    for (int i = 0; i < 2; ++i){
      uint4v u = row[tid + i*256];
#pragma unroll
      for (int j = 0; j < 4; ++j){
        float a = bf2f((unsigned short)(u[j] & 0xffffu));
        float b = bf2f((unsigned short)(u[j] >> 16));
        s += a + b; q += a*a + b*b;
      }
    }
  }
#pragma unroll
  for (int off = 32; off > 0; off >>= 1){
    s += __shfl_down(s, off);
    q += __shfl_down(q, off);
  }
  __shared__ float rs[4], rq[4];
  if ((tid & 63) == 0){ rs[tid >> 6] = s; rq[tid >> 6] = q; }
  __syncthreads();
  if (tid == 0){
    s = rs[0] + rs[1] + rs[2] + rs[3];
    q = rq[0] + rq[1] + rq[2] + rq[3];
    float mean = s * (1.0f/4096.0f);
    float var  = (q - 4096.0f*mean*mean) * (1.0f/4095.0f);
    stats[bc*2 + 0] = mean;
    stats[bc*2 + 1] = 1.0f / sqrtf(var + 1e-5f);
  }
}

// (c,l) -> (l,c) transpose for batch b.
// SPLIT: normalize, write rows [xhi(512)|xhi(512)|xlo(512)] (ldo=1536)
// else: plain bf16 (ldo=512)
template<bool SPLIT>
__global__ __launch_bounds__(256)
void norm_transpose(const void* __restrict__ X, const float* __restrict__ stats,
                    unsigned short* __restrict__ Out,
                    const unsigned int* __restrict__ flagPtr, int b)
{
  __shared__ float tile[64][65];
  const unsigned int fl = flagPtr[0];
  const int l0 = blockIdx.x * 64;
  const int c0 = blockIdx.y * 64;
  const int tid = threadIdx.x;
  const int tx = tid & 63, ty = tid >> 6;

#pragma unroll
  for (int p = 0; p < 16; ++p){
    const int cc = ty + p*4;
    const size_t src = ((size_t)b*512 + c0 + cc)*4096 + l0 + tx;
    tile[cc][tx] = fl ? ((const float*)X)[src]
                      : bf2f(((const unsigned short*)X)[src]);
  }
  __syncthreads();
  float mean = 0.f, inv = 1.f;
  if (SPLIT){
    mean = stats[(b*512 + c0 + tx)*2 + 0];
    inv  = stats[(b*512 + c0 + tx)*2 + 1];
  }
#pragma unroll
  for (int p = 0; p < 16; ++p){
    const int lj = ty + p*4;
    if (SPLIT){
      const float v = (tile[tx][lj] - mean) * inv;
      const size_t o = (size_t)(l0 + lj)*1536 + c0 + tx;
      const unsigned short hi = f2bf(v);
      Out[o] = hi;
      Out[o + 512] = hi;
      Out[o + 1024] = f2bf(v - bf2f(hi));
    } else {
      const size_t o = (size_t)(l0 + lj)*512 + c0 + tx;
      Out[o] = f2bf(tile[tx][lj]);
    }
  }
}

// f[l,m] = sum_{di,dj} s^2 * G[refl_l, refl_m]; rowwise softmax; write P bf16
__global__ __launch_bounds__(256)
void softmax_rows(const float* __restrict__ G, const float* __restrict__ scale_c,
                  unsigned short* __restrict__ P)
{
  const int l = blockIdx.x;
  const int yy = l >> 6, xx = l & 63;
  const int tid = threadIdx.x;

  float s2[9];
  const float* rowp[9];
#pragma unroll
  for (int di = 0; di < 3; ++di){
    int ry = yy + di - 1; ry = ry < 0 ? 1 : (ry > 63 ? 62 : ry);
#pragma unroll
    for (int dj = 0; dj < 3; ++dj){
      int rx = xx + dj - 1; rx = rx < 0 ? 1 : (rx > 63 ? 62 : rx);
      const int k = di*3 + dj;
      const float s = scale_c[k];
      s2[k] = s*s;
      rowp[k] = G + (size_t)(ry*64 + rx)*4096;
    }
  }

  float fv[16];
  float mx = -3.0e38f;
#pragma unroll
  for (int i = 0; i < 16; ++i){
    const int m = tid + i*256;
    const int my = m >> 6, mxo = m & 63;
    int cy[3], cx[3];
#pragma unroll
    for (int d = 0; d < 3; ++d){
      int t0 = my + d - 1;  cy[d] = (t0 < 0 ? 1 : (t0 > 63 ? 62 : t0))*64;
      int t1 = mxo + d - 1; cx[d] = (t1 < 0 ? 1 : (t1 > 63 ? 62 : t1));
    }
    float v = 0.f;
#pragma unroll
    for (int di = 0; di < 3; ++di)
#pragma unroll
      for (int dj = 0; dj < 3; ++dj)
        v = fmaf(s2[di*3+dj], rowp[di*3+dj][cy[di] + cx[dj]], v);
    fv[i] = v;
    mx = fmaxf(mx, v);
  }

  __shared__ float redA[4], redB[4];
#pragma unroll
  for (int off = 32; off > 0; off >>= 1) mx = fmaxf(mx, __shfl_down(mx, off));
  if ((tid & 63) == 0) redA[tid >> 6] = mx;
  __syncthreads();
  mx = fmaxf(fmaxf(redA[0], redA[1]), fmaxf(redA[2], redA[3]));

  float sum = 0.f;
#pragma unroll
  for (int i = 0; i < 16; ++i){ fv[i] = __expf(fv[i] - mx); sum += fv[i]; }
#pragma unroll
  for (int off = 32; off > 0; off >>= 1) sum += __shfl_down(sum, off);
  if ((tid & 63) == 0) redB[tid >> 6] = sum;
  __syncthreads();
  sum = redB[0] + redB[1] + redB[2] + redB[3];
  const float inv = 1.0f / sum;

  unsigned short* Prow = P + (size_t)l*4096;
#pragma unroll
  for (int i = 0; i < 16; ++i) Prow[tid + i*256] = f2bf(fv[i]*inv);
}

extern "C" void kernel_launch(void* const* d_in, const int* in_sizes, int n_in,
                              void* d_out, int out_size, void* d_ws, size_t ws_size,
                              hipStream_t stream)
{
  const void* content = d_in[0];
  const void* style   = d_in[1];
  const void* fusion  = d_in[2];
  const void* theta_w = d_in[3];
  const void* theta_b = d_in[4];
  const void* phi_w   = d_in[5];
  const void* phi_b   = d_in[6];
  const void* g_w     = d_in[7];
  const void* g_b     = d_in[8];
  const void* W_w     = d_in[9];
  const void* W_b     = d_in[10];
  const void* scale   = d_in[11];

  char* ws = (char*)d_ws;
  size_t off = 0;
  auto take = [&](size_t bytes)->char*{
    char* p = ws + off; off += (bytes + 255) & ~(size_t)255; return p;
  };

  unsigned int* flag  = (unsigned int*)take(256);
  float* scale_c      = (float*)take(256);
  float* tb_c         = (float*)take(1024);
  float* pb_c         = (float*)take(1024);
  float* gb_c         = (float*)take(1024);
  float* wb_c         = (float*)take(2048);
  float* statsC       = (float*)take(1024ull*2*4);
  float* statsS       = (float*)take(1024ull*2*4);
  unsigned short* wdup = (unsigned short*)take(2ull*256*1536*2); // theta|phi [hi|lo|hi]
  unsigned short* gwc  = (unsigned short*)take(256ull*512*2);
  unsigned short* wwc  = (unsigned short*)take(512ull*256*2);
  unsigned short* th   = (unsigned short*)take(4096ull*768*2);   // per-batch [hi|hi|lo]
  unsigned short* ph   = (unsigned short*)take(4096ull*768*2);   // per-batch [hi|lo|hi]
  unsigned short* gs   = (unsigned short*)take(256ull*4096*2);   // per-batch [o][m]
  unsigned short* yb   = (unsigned short*)take(4096ull*256*2);   // per-batch [l][o]
  float* G             = (float*)take(4096ull*4096*4);           // per-batch
  char* unionB         = take(4096ull*4096*2);                   // 32MB union
  unsigned short* xn   = (unsigned short*)unionB;
  unsigned short* sn   = (unsigned short*)(unionB + 4096ull*1536*2);
  unsigned short* fst  = (unsigned short*)(unionB + 2ull*4096*1536*2);
  unsigned short* P    = (unsigned short*)unionB;                // after xn/sn/fst dead
  float* partF          = G;                   // f32 partials overlay dead G
  unsigned short* partH = (unsigned short*)G;  // bf16 partials overlay dead G
  const size_t zS1 = 4096ull*256;   // 1M elems (th/ph/y/g slices)
  const size_t zSW = 512ull*4096;   // 2M elems (W slices)

  detect_prep<<<1, 256, 0, stream>>>(content, theta_b, phi_b, g_b, W_b, scale,
                                     flag, scale_c, tb_c, pb_c, gb_c, wb_c);
  conv_weights<<<dim3(512,4), 256, 0, stream>>>(theta_w, phi_w, g_w, W_w, flag,
                                                wdup, gwc, wwc);
  stats_kernel<<<1024, 256, 0, stream>>>(content, flag, statsC);
  stats_kernel<<<1024, 256, 0, stream>>>(style,   flag, statsS);

  for (int b = 0; b < 2; ++b){
    dim3 ntg(64, 8, 1);
    norm_transpose<true ><<<ntg, 256, 0, stream>>>(content, statsC, xn, flag, b);
    norm_transpose<true ><<<ntg, 256, 0, stream>>>(style,   statsS, sn, flag, b);
    norm_transpose<false><<<ntg, 256, 0, stream>>>(fusion,  nullptr, fst, flag, b);

    // theta: (4096x256) = xn(4096x1536)*wdup_t(256x1536)^T, split-K 8x192 (f32)
    gemm_bt<OUT_PART, BIAS_NONE><<<dim3(2,16,8), 256, 0, stream>>>(
        xn, 1536, wdup, 1536, 192, partF, 256, nullptr, 0, 0, nullptr, 0, zS1);
    reduce_part<8, OUT_SPLIT3, BIAS_COL, 8, false><<<4096, 256, 0, stream>>>(
        partF, zS1, tb_c, th, 768, 256, 512, nullptr, 0);
    // phi -> ph [hi|lo|hi]
    gemm_bt<OUT_PART, BIAS_NONE><<<dim3(2,16,8), 256, 0, stream>>>(
        sn, 1536, wdup + 256*1536, 1536, 192, partF, 256, nullptr, 0, 0, nullptr, 0, zS1);
    reduce_part<8, OUT_SPLIT3, BIAS_COL, 8, false><<<4096, 256, 0, stream>>>(
        partF, zS1, pb_c, ph, 768, 512, 256, nullptr, 0);
    // g: (256x4096) = gwc(256x512) * fst(4096x512)^T, split-K 8x64 (bf16)
    gemm_bt<OUT_PARTH, BIAS_NONE><<<dim3(32,1,8), 256, 0, stream>>>(
        gwc, 512, fst, 512, 64, partH, 4096, nullptr, 0, 0, nullptr, 0, zS1);
    reduce_part<8, OUT_BF16, BIAS_ROW, 12, true><<<4096, 256, 0, stream>>>(
        partH, zS1, gb_c, gs, 4096, 0, 0, nullptr, 0);
    // G = th * ph^T (f32), K=768 compensated product
    gemm_bt<OUT_F32, BIAS_NONE><<<dim3(32,16), 256, 0, stream>>>(
        th, 768, ph, 768, 768, G, 4096, nullptr, 0, 0, nullptr, 0, 0);
    // f-assembly + rowwise softmax -> P (bf16); P overlays dead xn/sn/fst
    softmax_rows<<<4096, 256, 0, stream>>>(G, scale_c, P);
    // y = P * gs^T : (4096x256), split-K 16x256, bf16 partials (overlay dead G)
    gemm_bt<OUT_PARTH, BIAS_NONE><<<dim3(2,16,16), 256, 0, stream>>>(
        P, 4096, gs, 4096, 256, partH, 256, nullptr, 0, 0, nullptr, 0, zS1);
    reduce_part<16, OUT_BF16, BIAS_NONE, 8, true><<<4096, 256, 0, stream>>>(
        partH, zS1, nullptr, yb, 256, 0, 0, nullptr, 0);
    // out = wwc(512x256) * yb(4096x256)^T + W_b, split-K 4x64 (f32 partials
    // overlay dead G); reduce applies row bias + flag dtype
    gemm_bt<OUT_PART, BIAS_NONE><<<dim3(32,2,4), 256, 0, stream>>>(
        wwc, 256, yb, 256, 64, partF, 4096, nullptr, 0, 0, nullptr, 0, zSW);
    reduce_part<4, OUT_FLAG, BIAS_ROW, 12, false><<<8192, 256, 0, stream>>>(
        partF, zSW, wb_c, d_out, 4096, 0, 0, flag, (size_t)b*512*4096);
  }
}

// Round 9
// 418.440 us; speedup vs baseline: 1.2336x; 1.2336x over previous
//
#include <hip/hip_runtime.h>
#include <stdint.h>

typedef __attribute__((ext_vector_type(8))) __bf16 bf16x8;
typedef __attribute__((ext_vector_type(4))) float f32x4;
typedef __attribute__((ext_vector_type(4))) unsigned int uint4v;

__device__ __forceinline__ float bf2f(unsigned short u){
  unsigned int x = ((unsigned int)u) << 16;
  return __builtin_bit_cast(float, x);
}
__device__ __forceinline__ unsigned short f2bf(float f){
  unsigned int x = __builtin_bit_cast(unsigned int, f);
  x += 0x7FFFu + ((x >> 16) & 1u);
  return (unsigned short)(x >> 16);
}

#define OUT_F32 0
#define OUT_BF16 1
#define OUT_SPLIT3 2
#define OUT_FLAG 3
#define OUT_PART 4
#define OUT_PARTH 5
#define BIAS_NONE 0
#define BIAS_ROW 1
#define BIAS_COL 2

// ---------- 128x128 tile GEMM (R7-proven: 64 VGPR, 4 blocks/CU) ----------
// Use for all small/split-K GEMMs. C = A * Bt^T, M,N mult 128, kchunk mult 32.
// Register staging + double-buffered LDS, one barrier per K-step.
// LDS: row r at byte r*64; 16B-chunk p of row r holds k-chunk (p ^ ((r>>1)&3)).
template<int OM, int BM>
__global__ __launch_bounds__(256)
void gemm_bt(const unsigned short* __restrict__ A, int lda,
             const unsigned short* __restrict__ Bt, int ldb,
             int kchunk, void* __restrict__ Out, int ldo,
             const float* __restrict__ bias,
             int dupOff, int loOff,
             const unsigned int* __restrict__ flagPtr, size_t outOff,
             size_t zStride)
{
  __shared__ uint4v AsmBuf[1024];   // 2 x 8KB
  __shared__ uint4v BsmBuf[1024];
  char* Asm = (char*)AsmBuf;
  char* Bsm = (char*)BsmBuf;

  const unsigned int fl = (OM == OUT_FLAG) ? flagPtr[0] : 0u;

  const int tid  = threadIdx.x;
  const int lane = tid & 63;
  const int wave = tid >> 6;
  const int wy = wave >> 1, wx = wave & 1;
  const int lm = lane & 15, quad = lane >> 4;
  const int tileM = blockIdx.y * 128;
  const int tileN = blockIdx.x * 128;
  const int z = blockIdx.z;

  A  += (size_t)z * kchunk;
  Bt += (size_t)z * kchunk;

  const int sr0 = tid >> 2, sc0 = tid & 3;
  const int sr1 = sr0 + 64;
  const size_t gA0 = (size_t)(tileM + sr0)*lda + ((sc0 ^ ((sr0 >> 1) & 3)) << 3);
  const size_t gA1 = (size_t)(tileM + sr1)*lda + ((sc0 ^ ((sr1 >> 1) & 3)) << 3);
  const size_t gB0 = (size_t)(tileN + sr0)*ldb + ((sc0 ^ ((sr0 >> 1) & 3)) << 3);
  const size_t gB1 = (size_t)(tileN + sr1)*ldb + ((sc0 ^ ((sr1 >> 1) & 3)) << 3);
  const int lOff0 = sr0*64 + sc0*16;
  const int lOff1 = sr1*64 + sc0*16;

  int aOff[4], bOff[4];
#pragma unroll
  for (int t = 0; t < 4; ++t){
    int ra = wy*64 + t*16 + lm;
    aOff[t] = ra*64 + ((quad ^ ((ra >> 1) & 3)) << 4);
    int rb = wx*64 + t*16 + lm;
    bOff[t] = rb*64 + ((quad ^ ((rb >> 1) & 3)) << 4);
  }

  f32x4 acc[4][4] = {};

  const int ksteps = kchunk >> 5;
  uint4v a0v = *(const uint4v*)(A + gA0);
  uint4v a1v = *(const uint4v*)(A + gA1);
  uint4v b0v = *(const uint4v*)(Bt + gB0);
  uint4v b1v = *(const uint4v*)(Bt + gB1);

  for (int kt = 0; kt < ksteps; ++kt){
    char* As = Asm + (kt & 1)*8192;
    char* Bs = Bsm + (kt & 1)*8192;
    *(uint4v*)(As + lOff0) = a0v;
    *(uint4v*)(As + lOff1) = a1v;
    *(uint4v*)(Bs + lOff0) = b0v;
    *(uint4v*)(Bs + lOff1) = b1v;
    __syncthreads();
    if (kt + 1 < ksteps){
      const unsigned short* Ak = A + (kt + 1)*32;
      const unsigned short* Bk = Bt + (kt + 1)*32;
      a0v = *(const uint4v*)(Ak + gA0);
      a1v = *(const uint4v*)(Ak + gA1);
      b0v = *(const uint4v*)(Bk + gB0);
      b1v = *(const uint4v*)(Bk + gB1);
    }
    bf16x8 af[4], bfr[4];
#pragma unroll
    for (int t = 0; t < 4; ++t){
      af[t]  = __builtin_bit_cast(bf16x8, *(const uint4v*)(As + aOff[t]));
      bfr[t] = __builtin_bit_cast(bf16x8, *(const uint4v*)(Bs + bOff[t]));
    }
#pragma unroll
    for (int tm = 0; tm < 4; ++tm)
#pragma unroll
      for (int tn = 0; tn < 4; ++tn)
        acc[tm][tn] = __builtin_amdgcn_mfma_f32_16x16x32_bf16(af[tm], bfr[tn], acc[tm][tn], 0, 0, 0);
  }

  // D row = quad*4 + reg, col = lane&15
#pragma unroll
  for (int tm = 0; tm < 4; ++tm){
    const int rowb = tileM + wy*64 + tm*16 + quad*4;
#pragma unroll
    for (int tn = 0; tn < 4; ++tn){
      const int col = tileN + wx*64 + tn*16 + lm;
      float bcv = 0.f;
      if (BM == BIAS_COL) bcv = bias[col];
#pragma unroll
      for (int r = 0; r < 4; ++r){
        float v = acc[tm][tn][r];
        const int row = rowb + r;
        if (BM == BIAS_ROW) v += bias[row];
        if (BM == BIAS_COL) v += bcv;
        const size_t idx = (size_t)row*ldo + col;
        if (OM == OUT_F32){
          ((float*)Out)[idx] = v;
        } else if (OM == OUT_BF16){
          ((unsigned short*)Out)[idx] = f2bf(v);
        } else if (OM == OUT_SPLIT3){
          unsigned short hi = f2bf(v);
          unsigned short lo = f2bf(v - bf2f(hi));
          unsigned short* O = (unsigned short*)Out;
          O[idx] = hi; O[idx + dupOff] = hi; O[idx + loOff] = lo;
        } else if (OM == OUT_PART){
          ((float*)Out)[(size_t)z*zStride + idx] = v;
        } else if (OM == OUT_PARTH){
          ((unsigned short*)Out)[(size_t)z*zStride + idx] = f2bf(v);
        } else { // OUT_FLAG
          if (fl) ((float*)Out)[outOff + idx] = v;
          else    ((unsigned short*)Out)[outOff + idx] = f2bf(v);
        }
      }
    }
  }
}

// ---------- 256x128 tile GEMM — G-GEMM ONLY (K=768, 24 K-steps amortize the
// big tile; R8 measured it ≤40us vs 42.4 for the 128-tile, but it regresses
// split-K GEMMs with few K-steps). f32 output, no bias. ----------
__global__ __launch_bounds__(256)
void gemm_big(const unsigned short* __restrict__ A, int lda,
              const unsigned short* __restrict__ Bt, int ldb,
              int K, float* __restrict__ Out, int ldo)
{
  __shared__ uint4v AsmBuf[2048];   // 2 x 16KB
  __shared__ uint4v BsmBuf[1024];   // 2 x 8KB
  char* Asm = (char*)AsmBuf;
  char* Bsm = (char*)BsmBuf;

  const int tid  = threadIdx.x;
  const int lane = tid & 63;
  const int wave = tid >> 6;
  const int wy = wave >> 1, wx = wave & 1;
  const int lm = lane & 15, quad = lane >> 4;
  const int tileM = blockIdx.y * 256;
  const int tileN = blockIdx.x * 128;

  const int sr = tid >> 2, sc = tid & 3;
  size_t gA[4]; int lA[4];
  size_t gB[2]; int lB[2];
#pragma unroll
  for (int i = 0; i < 4; ++i){
    const int r = sr + 64*i;
    gA[i] = (size_t)(tileM + r)*lda + ((sc ^ ((r >> 1) & 3)) << 3);
    lA[i] = r*64 + sc*16;
  }
#pragma unroll
  for (int i = 0; i < 2; ++i){
    const int r = sr + 64*i;
    gB[i] = (size_t)(tileN + r)*ldb + ((sc ^ ((r >> 1) & 3)) << 3);
    lB[i] = r*64 + sc*16;
  }

  int aOff[8], bOff[4];
#pragma unroll
  for (int t = 0; t < 8; ++t){
    const int ra = wy*128 + t*16 + lm;
    aOff[t] = ra*64 + ((quad ^ ((ra >> 1) & 3)) << 4);
  }
#pragma unroll
  for (int t = 0; t < 4; ++t){
    const int rb = wx*64 + t*16 + lm;
    bOff[t] = rb*64 + ((quad ^ ((rb >> 1) & 3)) << 4);
  }

  f32x4 acc[8][4] = {};

  const int ksteps = K >> 5;
  uint4v av[4], bv[2];
#pragma unroll
  for (int i = 0; i < 4; ++i) av[i] = *(const uint4v*)(A + gA[i]);
#pragma unroll
  for (int i = 0; i < 2; ++i) bv[i] = *(const uint4v*)(Bt + gB[i]);

  for (int kt = 0; kt < ksteps; ++kt){
    char* As = Asm + (kt & 1)*16384;
    char* Bs = Bsm + (kt & 1)*8192;
#pragma unroll
    for (int i = 0; i < 4; ++i) *(uint4v*)(As + lA[i]) = av[i];
#pragma unroll
    for (int i = 0; i < 2; ++i) *(uint4v*)(Bs + lB[i]) = bv[i];
    __syncthreads();
    if (kt + 1 < ksteps){
      const unsigned short* Ak = A + (kt + 1)*32;
      const unsigned short* Bk = Bt + (kt + 1)*32;
#pragma unroll
      for (int i = 0; i < 4; ++i) av[i] = *(const uint4v*)(Ak + gA[i]);
#pragma unroll
      for (int i = 0; i < 2; ++i) bv[i] = *(const uint4v*)(Bk + gB[i]);
    }
    bf16x8 af[8], bfr[4];
#pragma unroll
    for (int t = 0; t < 8; ++t)
      af[t] = __builtin_bit_cast(bf16x8, *(const uint4v*)(As + aOff[t]));
#pragma unroll
    for (int t = 0; t < 4; ++t)
      bfr[t] = __builtin_bit_cast(bf16x8, *(const uint4v*)(Bs + bOff[t]));
#pragma unroll
    for (int tm = 0; tm < 8; ++tm)
#pragma unroll
      for (int tn = 0; tn < 4; ++tn)
        acc[tm][tn] = __builtin_amdgcn_mfma_f32_16x16x32_bf16(af[tm], bfr[tn], acc[tm][tn], 0, 0, 0);
  }

#pragma unroll
  for (int tm = 0; tm < 8; ++tm){
    const int rowb = tileM + wy*128 + tm*16 + quad*4;
#pragma unroll
    for (int tn = 0; tn < 4; ++tn){
      const int col = tileN + wx*64 + tn*16 + lm;
#pragma unroll
      for (int r = 0; r < 4; ++r)
        Out[(size_t)(rowb + r)*ldo + col] = acc[tm][tn][r];
    }
  }
}

// sum S partial slices (flat [S][rows*cols]) -> epilogue.
// CSH = log2(cols). HALFP: bf16 partials.
template<int S, int OM, int BM, int CSH, bool HALFP>
__global__ __launch_bounds__(256)
void reduce_part(const void* __restrict__ part, size_t zStride,
                 const float* __restrict__ bias,
                 void* __restrict__ Out, int ldo,
                 int dupOff, int loOff,
                 const unsigned int* __restrict__ flagPtr, size_t outOff)
{
  const size_t i = (size_t)blockIdx.x*256 + threadIdx.x;
  const int row = (int)(i >> CSH);
  const int col = (int)(i & ((1u << CSH) - 1u));
  float v = 0.f;
#pragma unroll
  for (int s = 0; s < S; ++s){
    if (HALFP) v += bf2f(((const unsigned short*)part)[(size_t)s*zStride + i]);
    else       v += ((const float*)part)[(size_t)s*zStride + i];
  }
  if (BM == BIAS_ROW) v += bias[row];
  if (BM == BIAS_COL) v += bias[col];
  const size_t o = (size_t)row*ldo + col;
  if (OM == OUT_SPLIT3){
    unsigned short hi = f2bf(v);
    unsigned short lo = f2bf(v - bf2f(hi));
    unsigned short* O = (unsigned short*)Out;
    O[o] = hi; O[o + dupOff] = hi; O[o + loOff] = lo;
  } else if (OM == OUT_BF16){
    ((unsigned short*)Out)[o] = f2bf(v);
  } else { // OUT_FLAG
    if (flagPtr[0]) ((float*)Out)[outOff + o] = v;
    else            ((unsigned short*)Out)[outOff + o] = f2bf(v);
  }
}

// dtype vote + scalar/bias canonicalization (f32 canon)
__global__ __launch_bounds__(256)
void detect_prep(const void* __restrict__ content,
                 const void* tb, const void* pb, const void* gb, const void* wb,
                 const void* sc,
                 unsigned int* __restrict__ flag, float* __restrict__ scale_c,
                 float* tb_c, float* pb_c, float* gb_c, float* wb_c)
{
  __shared__ int cnt;
  __shared__ unsigned int flg;
  const int tid = threadIdx.x;
  if (tid == 0) cnt = 0;
  __syncthreads();
  unsigned int w = ((const unsigned int*)content)[tid];
  int e = (w >> 23) & 0xFF;
  if (e >= 0x70 && e <= 0x8F) atomicAdd(&cnt, 1);
  __syncthreads();
  if (tid == 0){ flg = (cnt >= 128) ? 1u : 0u; flag[0] = flg; }
  __syncthreads();
  const unsigned int f = flg;
  auto rd = [&](const void* p, int i)->float{
    return f ? ((const float*)p)[i] : bf2f(((const unsigned short*)p)[i]);
  };
  if (tid < 9) scale_c[tid] = rd(sc, tid);
  tb_c[tid] = rd(tb, tid);
  pb_c[tid] = rd(pb, tid);
  gb_c[tid] = rd(gb, tid);
  wb_c[tid] = rd(wb, tid);
  wb_c[tid + 256] = rd(wb, tid + 256);
}

// canonicalize weights: theta/phi -> wdup rows [whi(512)|wlo(512)|whi(512)],
// g_w -> gwc bf16, W_w -> wwc bf16
__global__ __launch_bounds__(256)
void conv_weights(const void* tw, const void* pw, const void* gw, const void* www,
                  const unsigned int* __restrict__ flagPtr,
                  unsigned short* __restrict__ wdup,
                  unsigned short* __restrict__ gwc,
                  unsigned short* __restrict__ wwc)
{
  const unsigned int fl = flagPtr[0];
  const int sec = blockIdx.y;
  const int idx = blockIdx.x*256 + threadIdx.x;
  auto rd = [&](const void* p, int i)->float{
    return fl ? ((const float*)p)[i] : bf2f(((const unsigned short*)p)[i]);
  };
  if (sec < 2){
    const void* w = sec ? pw : tw;
    const int o = idx >> 9, c = idx & 511;
    float v = rd(w, o*512 + c);
    unsigned short hi = f2bf(v);
    unsigned short lo = f2bf(v - bf2f(hi));
    unsigned short* base = wdup + (size_t)sec*256*1536 + o*1536;
    base[c] = hi; base[512 + c] = lo; base[1024 + c] = hi;
  } else if (sec == 2){
    const int o = idx >> 9, c = idx & 511;
    gwc[o*512 + c] = f2bf(rd(gw, o*512 + c));
  } else {
    const int o = idx >> 8, c = idx & 255;
    wwc[o*256 + c] = f2bf(rd(www, o*256 + c));
  }
}

// per-(b,c) mean / invstd over 4096 spatial elems (unbiased var)
__global__ __launch_bounds__(256)
void stats_kernel(const void* __restrict__ X, const unsigned int* __restrict__ flagPtr,
                  float* __restrict__ stats)
{
  const unsigned int fl = flagPtr[0];
  const int bc = blockIdx.x;
  const int tid = threadIdx.x;
  float s = 0.f, q = 0.f;
  if (fl){
    const f32x4* row = (const f32x4*)((const float*)X + (size_t)bc*4096);
#pragma unroll
    for (int i = 0; i < 4; ++i){
      f32x4 v = row[tid + i*256];
#pragma unroll
      for (int j = 0; j < 4; ++j){ s += v[j]; q += v[j]*v[j]; }
    }
  } else {
    const uint4v* row = (const uint4v*)((const unsigned short*)X + (size_t)bc*4096);
#pragma unroll
    for (int i = 0; i < 2; ++i){
      uint4v u = row[tid + i*256];
#pragma unroll
      for (int j = 0; j < 4; ++j){
        float a = bf2f((unsigned short)(u[j] & 0xffffu));
        float b = bf2f((unsigned short)(u[j] >> 16));
        s += a + b; q += a*a + b*b;
      }
    }
  }
#pragma unroll
  for (int off = 32; off > 0; off >>= 1){
    s += __shfl_down(s, off);
    q += __shfl_down(q, off);
  }
  __shared__ float rs[4], rq[4];
  if ((tid & 63) == 0){ rs[tid >> 6] = s; rq[tid >> 6] = q; }
  __syncthreads();
  if (tid == 0){
    s = rs[0] + rs[1] + rs[2] + rs[3];
    q = rq[0] + rq[1] + rq[2] + rq[3];
    float mean = s * (1.0f/4096.0f);
    float var  = (q - 4096.0f*mean*mean) * (1.0f/4095.0f);
    stats[bc*2 + 0] = mean;
    stats[bc*2 + 1] = 1.0f / sqrtf(var + 1e-5f);
  }
}

// (c,l) -> (l,c) transpose, BOTH batches (grid.z=2), out row = b*4096 + l.
// SPLIT: normalize, write rows [xhi|xhi|xlo] (ldo=1536); else bf16 (ldo=512)
template<bool SPLIT>
__global__ __launch_bounds__(256)
void norm_transpose(const void* __restrict__ X, const float* __restrict__ stats,
                    unsigned short* __restrict__ Out,
                    const unsigned int* __restrict__ flagPtr)
{
  __shared__ float tile[64][65];
  const unsigned int fl = flagPtr[0];
  const int b  = blockIdx.z;
  const int l0 = blockIdx.x * 64;
  const int c0 = blockIdx.y * 64;
  const int tid = threadIdx.x;
  const int tx = tid & 63, ty = tid >> 6;

#pragma unroll
  for (int p = 0; p < 16; ++p){
    const int cc = ty + p*4;
    const size_t src = ((size_t)b*512 + c0 + cc)*4096 + l0 + tx;
    tile[cc][tx] = fl ? ((const float*)X)[src]
                      : bf2f(((const unsigned short*)X)[src]);
  }
  __syncthreads();
  float mean = 0.f, inv = 1.f;
  if (SPLIT){
    mean = stats[(b*512 + c0 + tx)*2 + 0];
    inv  = stats[(b*512 + c0 + tx)*2 + 1];
  }
#pragma unroll
  for (int p = 0; p < 16; ++p){
    const int lj = ty + p*4;
    const size_t rowOut = (size_t)b*4096 + l0 + lj;
    if (SPLIT){
      const float v = (tile[tx][lj] - mean) * inv;
      const size_t o = rowOut*1536 + c0 + tx;
      const unsigned short hi = f2bf(v);
      Out[o] = hi;
      Out[o + 512] = hi;
      Out[o + 1024] = f2bf(v - bf2f(hi));
    } else {
      const size_t o = rowOut*512 + c0 + tx;
      Out[o] = f2bf(tile[tx][lj]);
    }
  }
}

// f[l,m] = sum_{di,dj} s^2 * G[refl_l, refl_m]; rowwise softmax; write P bf16
__global__ __launch_bounds__(256)
void softmax_rows(const float* __restrict__ G, const float* __restrict__ scale_c,
                  unsigned short* __restrict__ P)
{
  const int l = blockIdx.x;
  const int yy = l >> 6, xx = l & 63;
  const int tid = threadIdx.x;

  float s2[9];
  const float* rowp[9];
#pragma unroll
  for (int di = 0; di < 3; ++di){
    int ry = yy + di - 1; ry = ry < 0 ? 1 : (ry > 63 ? 62 : ry);
#pragma unroll
    for (int dj = 0; dj < 3; ++dj){
      int rx = xx + dj - 1; rx = rx < 0 ? 1 : (rx > 63 ? 62 : rx);
      const int k = di*3 + dj;
      const float s = scale_c[k];
      s2[k] = s*s;
      rowp[k] = G + (size_t)(ry*64 + rx)*4096;
    }
  }

  float fv[16];
  float mx = -3.0e38f;
#pragma unroll
  for (int i = 0; i < 16; ++i){
    const int m = tid + i*256;
    const int my = m >> 6, mxo = m & 63;
    int cy[3], cx[3];
#pragma unroll
    for (int d = 0; d < 3; ++d){
      int t0 = my + d - 1;  cy[d] = (t0 < 0 ? 1 : (t0 > 63 ? 62 : t0))*64;
      int t1 = mxo + d - 1; cx[d] = (t1 < 0 ? 1 : (t1 > 63 ? 62 : t1));
    }
    float v = 0.f;
#pragma unroll
    for (int di = 0; di < 3; ++di)
#pragma unroll
      for (int dj = 0; dj < 3; ++dj)
        v = fmaf(s2[di*3+dj], rowp[di*3+dj][cy[di] + cx[dj]], v);
    fv[i] = v;
    mx = fmaxf(mx, v);
  }

  __shared__ float redA[4], redB[4];
#pragma unroll
  for (int off = 32; off > 0; off >>= 1) mx = fmaxf(mx, __shfl_down(mx, off));
  if ((tid & 63) == 0) redA[tid >> 6] = mx;
  __syncthreads();
  mx = fmaxf(fmaxf(redA[0], redA[1]), fmaxf(redA[2], redA[3]));

  float sum = 0.f;
#pragma unroll
  for (int i = 0; i < 16; ++i){ fv[i] = __expf(fv[i] - mx); sum += fv[i]; }
#pragma unroll
  for (int off = 32; off > 0; off >>= 1) sum += __shfl_down(sum, off);
  if ((tid & 63) == 0) redB[tid >> 6] = sum;
  __syncthreads();
  sum = redB[0] + redB[1] + redB[2] + redB[3];
  const float inv = 1.0f / sum;

  unsigned short* Prow = P + (size_t)l*4096;
#pragma unroll
  for (int i = 0; i < 16; ++i) Prow[tid + i*256] = f2bf(fv[i]*inv);
}

extern "C" void kernel_launch(void* const* d_in, const int* in_sizes, int n_in,
                              void* d_out, int out_size, void* d_ws, size_t ws_size,
                              hipStream_t stream)
{
  const void* content = d_in[0];
  const void* style   = d_in[1];
  const void* fusion  = d_in[2];
  const void* theta_w = d_in[3];
  const void* theta_b = d_in[4];
  const void* phi_w   = d_in[5];
  const void* phi_b   = d_in[6];
  const void* g_w     = d_in[7];
  const void* g_b     = d_in[8];
  const void* W_w     = d_in[9];
  const void* W_b     = d_in[10];
  const void* scale   = d_in[11];

  char* ws = (char*)d_ws;
  size_t off = 0;
  auto take = [&](size_t bytes)->char*{
    char* p = ws + off; off += (bytes + 255) & ~(size_t)255; return p;
  };

  unsigned int* flag  = (unsigned int*)take(256);
  float* scale_c      = (float*)take(256);
  float* tb_c         = (float*)take(1024);
  float* pb_c         = (float*)take(1024);
  float* gb_c         = (float*)take(1024);
  float* wb_c         = (float*)take(2048);
  float* statsC       = (float*)take(1024ull*2*4);
  float* statsS       = (float*)take(1024ull*2*4);
  unsigned short* wdup = (unsigned short*)take(2ull*256*1536*2); // theta|phi [hi|lo|hi]
  unsigned short* gwc  = (unsigned short*)take(256ull*512*2);
  unsigned short* wwc  = (unsigned short*)take(512ull*256*2);
  unsigned short* th   = (unsigned short*)take(8192ull*768*2);   // both batches [hi|hi|lo]
  unsigned short* ph   = (unsigned short*)take(8192ull*768*2);   // both batches [hi|lo|hi]
  unsigned short* gs   = (unsigned short*)take(256ull*8192*2);   // [o][b*4096+m]
  unsigned short* yb   = (unsigned short*)take(2ull*4096*256*2); // [b][l][o]
  float* G             = (float*)take(4096ull*4096*4);           // per-batch (phase2)
  char* unionC         = take(2ull*4096*1536*2*2 + 2ull*4096*512*2); // 56MB
  unsigned short* xn   = (unsigned short*)unionC;                       // 24MB (8192x1536)
  unsigned short* sn   = (unsigned short*)(unionC + 8192ull*1536*2);    // 24MB
  unsigned short* fst  = (unsigned short*)(unionC + 2ull*8192*1536*2);  // 8MB (8192x512)
  unsigned short* P    = (unsigned short*)unionC;                // phase2: overlays xn
  float* partF          = G;                   // f32 partials overlay dead G
  unsigned short* partH = (unsigned short*)G;  // bf16 partials overlay dead G
  const size_t zTP = 8192ull*256;   // theta/phi slices (2M elems)
  const size_t zG  = 256ull*8192;   // g slices (2M elems)
  const size_t zY  = 4096ull*256;   // y slices (1M elems)
  const size_t zW  = 512ull*4096;   // W slices (2M elems)

  // ---- phase 1: both batches ----
  detect_prep<<<1, 256, 0, stream>>>(content, theta_b, phi_b, g_b, W_b, scale,
                                     flag, scale_c, tb_c, pb_c, gb_c, wb_c);
  conv_weights<<<dim3(512,4), 256, 0, stream>>>(theta_w, phi_w, g_w, W_w, flag,
                                                wdup, gwc, wwc);
  stats_kernel<<<1024, 256, 0, stream>>>(content, flag, statsC);
  stats_kernel<<<1024, 256, 0, stream>>>(style,   flag, statsS);
  dim3 ntg(64, 8, 2);
  norm_transpose<true ><<<ntg, 256, 0, stream>>>(content, statsC, xn, flag);
  norm_transpose<true ><<<ntg, 256, 0, stream>>>(style,   statsS, sn, flag);
  norm_transpose<false><<<ntg, 256, 0, stream>>>(fusion,  nullptr, fst, flag);

  // theta: (8192x256) = xn(8192x1536)*wdup_t(256x1536)^T, split-K 4x384 (f32)
  gemm_bt<OUT_PART, BIAS_NONE><<<dim3(2,64,4), 256, 0, stream>>>(
      xn, 1536, wdup, 1536, 384, partF, 256, nullptr, 0, 0, nullptr, 0, zTP);
  reduce_part<4, OUT_SPLIT3, BIAS_COL, 8, false><<<8192, 256, 0, stream>>>(
      partF, zTP, tb_c, th, 768, 256, 512, nullptr, 0);
  // phi -> ph [hi|lo|hi]
  gemm_bt<OUT_PART, BIAS_NONE><<<dim3(2,64,4), 256, 0, stream>>>(
      sn, 1536, wdup + 256*1536, 1536, 384, partF, 256, nullptr, 0, 0, nullptr, 0, zTP);
  reduce_part<4, OUT_SPLIT3, BIAS_COL, 8, false><<<8192, 256, 0, stream>>>(
      partF, zTP, pb_c, ph, 768, 512, 256, nullptr, 0);
  // g: (256x8192) = gwc(256x512) * fst(8192x512)^T, split-K 4x128 (bf16)
  gemm_bt<OUT_PARTH, BIAS_NONE><<<dim3(64,2,4), 256, 0, stream>>>(
      gwc, 512, fst, 512, 128, partH, 8192, nullptr, 0, 0, nullptr, 0, zG);
  reduce_part<4, OUT_BF16, BIAS_ROW, 13, true><<<8192, 256, 0, stream>>>(
      partH, zG, gb_c, gs, 8192, 0, 0, nullptr, 0);

  // ---- phase 2: per batch ----
  for (int b = 0; b < 2; ++b){
    const unsigned short* thb = th + (size_t)b*4096*768;
    const unsigned short* phb = ph + (size_t)b*4096*768;
    // G = th * ph^T (f32), K=768; 256x128 tile (24 K-steps amortize)
    gemm_big<<<dim3(32,16), 256, 0, stream>>>(thb, 768, phb, 768, 768, G, 4096);
    // f-assembly + rowwise softmax -> P (overlays dead xn region)
    softmax_rows<<<4096, 256, 0, stream>>>(G, scale_c, P);
    // y = P * gs_b^T : (4096x256), split-K 8x512, bf16 partials (overlay dead G)
    gemm_bt<OUT_PARTH, BIAS_NONE><<<dim3(2,32,8), 256, 0, stream>>>(
        P, 4096, gs + (size_t)b*4096, 8192, 512, partH, 256, nullptr, 0, 0, nullptr, 0, zY);
    reduce_part<8, OUT_BF16, BIAS_NONE, 8, true><<<4096, 256, 0, stream>>>(
        partH, zY, nullptr, yb + (size_t)b*4096*256, 256, 0, 0, nullptr, 0);
    // out = wwc(512x256) * yb_b(4096x256)^T + W_b, split-K 2x128 (f32 overlay G)
    gemm_bt<OUT_PART, BIAS_NONE><<<dim3(32,4,2), 256, 0, stream>>>(
        wwc, 256, yb + (size_t)b*4096*256, 256, 128, partF, 4096, nullptr, 0, 0, nullptr, 0, zW);
    reduce_part<2, OUT_FLAG, BIAS_ROW, 12, false><<<8192, 256, 0, stream>>>(
        partF, zW, wb_c, d_out, 4096, 0, 0, flag, (size_t)b*512*4096);
  }
}

// Round 10
// 394.452 us; speedup vs baseline: 1.3086x; 1.0608x over previous
//
#include <hip/hip_runtime.h>
#include <stdint.h>

typedef __attribute__((ext_vector_type(8))) __bf16 bf16x8;
typedef __attribute__((ext_vector_type(4))) float f32x4;
typedef __attribute__((ext_vector_type(4))) unsigned int uint4v;

__device__ __forceinline__ float bf2f(unsigned short u){
  unsigned int x = ((unsigned int)u) << 16;
  return __builtin_bit_cast(float, x);
}
__device__ __forceinline__ unsigned short f2bf(float f){
  unsigned int x = __builtin_bit_cast(unsigned int, f);
  x += 0x7FFFu + ((x >> 16) & 1u);
  return (unsigned short)(x >> 16);
}

#define OUT_PART 4
#define OUT_PARTH 5

// ---------- 128x128 tile GEMM (R7-proven: 64 VGPR, 4 blocks/CU) ----------
// C = A * Bt^T. blockIdx.z: slice = z & sMask, batch = z >> sShift.
// A += slice*kchunk + batch*aBatch; Bt += slice*kchunk + batch*bBatch.
// Partials (f32 or bf16) written at z*zStride.
// Register staging + double-buffered LDS, one barrier per K-step.
// LDS: row r at byte r*64; 16B-chunk p of row r holds k-chunk (p ^ ((r>>1)&3)).
template<int OM>
__global__ __launch_bounds__(256)
void gemm_bt(const unsigned short* __restrict__ A, int lda,
             const unsigned short* __restrict__ Bt, int ldb,
             int kchunk, void* __restrict__ Out, int ldo,
             size_t zStride, size_t aBatch, size_t bBatch,
             int sMask, int sShift)
{
  __shared__ uint4v AsmBuf[1024];   // 2 x 8KB
  __shared__ uint4v BsmBuf[1024];
  char* Asm = (char*)AsmBuf;
  char* Bsm = (char*)BsmBuf;

  const int tid  = threadIdx.x;
  const int lane = tid & 63;
  const int wave = tid >> 6;
  const int wy = wave >> 1, wx = wave & 1;
  const int lm = lane & 15, quad = lane >> 4;
  const int tileM = blockIdx.y * 128;
  const int tileN = blockIdx.x * 128;
  const int z = blockIdx.z;
  const int slice = z & sMask;
  const int batch = z >> sShift;

  A  += (size_t)slice*kchunk + (size_t)batch*aBatch;
  Bt += (size_t)slice*kchunk + (size_t)batch*bBatch;

  const int sr0 = tid >> 2, sc0 = tid & 3;
  const int sr1 = sr0 + 64;
  const size_t gA0 = (size_t)(tileM + sr0)*lda + ((sc0 ^ ((sr0 >> 1) & 3)) << 3);
  const size_t gA1 = (size_t)(tileM + sr1)*lda + ((sc0 ^ ((sr1 >> 1) & 3)) << 3);
  const size_t gB0 = (size_t)(tileN + sr0)*ldb + ((sc0 ^ ((sr0 >> 1) & 3)) << 3);
  const size_t gB1 = (size_t)(tileN + sr1)*ldb + ((sc0 ^ ((sr1 >> 1) & 3)) << 3);
  const int lOff0 = sr0*64 + sc0*16;
  const int lOff1 = sr1*64 + sc0*16;

  int aOff[4], bOff[4];
#pragma unroll
  for (int t = 0; t < 4; ++t){
    int ra = wy*64 + t*16 + lm;
    aOff[t] = ra*64 + ((quad ^ ((ra >> 1) & 3)) << 4);
    int rb = wx*64 + t*16 + lm;
    bOff[t] = rb*64 + ((quad ^ ((rb >> 1) & 3)) << 4);
  }

  f32x4 acc[4][4] = {};

  const int ksteps = kchunk >> 5;
  uint4v a0v = *(const uint4v*)(A + gA0);
  uint4v a1v = *(const uint4v*)(A + gA1);
  uint4v b0v = *(const uint4v*)(Bt + gB0);
  uint4v b1v = *(const uint4v*)(Bt + gB1);

  for (int kt = 0; kt < ksteps; ++kt){
    char* As = Asm + (kt & 1)*8192;
    char* Bs = Bsm + (kt & 1)*8192;
    *(uint4v*)(As + lOff0) = a0v;
    *(uint4v*)(As + lOff1) = a1v;
    *(uint4v*)(Bs + lOff0) = b0v;
    *(uint4v*)(Bs + lOff1) = b1v;
    __syncthreads();
    if (kt + 1 < ksteps){
      const unsigned short* Ak = A + (kt + 1)*32;
      const unsigned short* Bk = Bt + (kt + 1)*32;
      a0v = *(const uint4v*)(Ak + gA0);
      a1v = *(const uint4v*)(Ak + gA1);
      b0v = *(const uint4v*)(Bk + gB0);
      b1v = *(const uint4v*)(Bk + gB1);
    }
    bf16x8 af[4], bfr[4];
#pragma unroll
    for (int t = 0; t < 4; ++t){
      af[t]  = __builtin_bit_cast(bf16x8, *(const uint4v*)(As + aOff[t]));
      bfr[t] = __builtin_bit_cast(bf16x8, *(const uint4v*)(Bs + bOff[t]));
    }
#pragma unroll
    for (int tm = 0; tm < 4; ++tm)
#pragma unroll
      for (int tn = 0; tn < 4; ++tn)
        acc[tm][tn] = __builtin_amdgcn_mfma_f32_16x16x32_bf16(af[tm], bfr[tn], acc[tm][tn], 0, 0, 0);
  }

  // D row = quad*4 + reg, col = lane&15
#pragma unroll
  for (int tm = 0; tm < 4; ++tm){
    const int rowb = tileM + wy*64 + tm*16 + quad*4;
#pragma unroll
    for (int tn = 0; tn < 4; ++tn){
      const int col = tileN + wx*64 + tn*16 + lm;
#pragma unroll
      for (int r = 0; r < 4; ++r){
        const float v = acc[tm][tn][r];
        const size_t idx = (size_t)z*zStride + (size_t)(rowb + r)*ldo + col;
        if (OM == OUT_PART) ((float*)Out)[idx] = v;
        else                ((unsigned short*)Out)[idx] = f2bf(v);
      }
    }
  }
}

// ---------- 256x128 tile GEMM — G-GEMM (K=768, 24 K-steps amortize the big
// tile). LDS-BW-bound (R9: 72KB LDS/block-K-step -> ~1125cyc vs 307 MFMA cyc
// at 2 blocks/CU => MfmaUtil 25%). Both batches in one dispatch via z. ----------
__global__ __launch_bounds__(256)
void gemm_big(const unsigned short* __restrict__ A, int lda,
              const unsigned short* __restrict__ Bt, int ldb,
              int K, float* __restrict__ Out, int ldo,
              size_t aBatch, size_t bBatch, size_t oBatch)
{
  __shared__ uint4v AsmBuf[2048];   // 2 x 16KB
  __shared__ uint4v BsmBuf[1024];   // 2 x 8KB
  char* Asm = (char*)AsmBuf;
  char* Bsm = (char*)BsmBuf;

  const int tid  = threadIdx.x;
  const int lane = tid & 63;
  const int wave = tid >> 6;
  const int wy = wave >> 1, wx = wave & 1;
  const int lm = lane & 15, quad = lane >> 4;
  const int tileM = blockIdx.y * 256;
  const int tileN = blockIdx.x * 128;
  const int z = blockIdx.z;

  A  += (size_t)z*aBatch;
  Bt += (size_t)z*bBatch;
  Out += (size_t)z*oBatch;

  const int sr = tid >> 2, sc = tid & 3;
  size_t gA[4]; int lA[4];
  size_t gB[2]; int lB[2];
#pragma unroll
  for (int i = 0; i < 4; ++i){
    const int r = sr + 64*i;
    gA[i] = (size_t)(tileM + r)*lda + ((sc ^ ((r >> 1) & 3)) << 3);
    lA[i] = r*64 + sc*16;
  }
#pragma unroll
  for (int i = 0; i < 2; ++i){
    const int r = sr + 64*i;
    gB[i] = (size_t)(tileN + r)*ldb + ((sc ^ ((r >> 1) & 3)) << 3);
    lB[i] = r*64 + sc*16;
  }

  int aOff[8], bOff[4];
#pragma unroll
  for (int t = 0; t < 8; ++t){
    const int ra = wy*128 + t*16 + lm;
    aOff[t] = ra*64 + ((quad ^ ((ra >> 1) & 3)) << 4);
  }
#pragma unroll
  for (int t = 0; t < 4; ++t){
    const int rb = wx*64 + t*16 + lm;
    bOff[t] = rb*64 + ((quad ^ ((rb >> 1) & 3)) << 4);
  }

  f32x4 acc[8][4] = {};

  const int ksteps = K >> 5;
  uint4v av[4], bv[2];
#pragma unroll
  for (int i = 0; i < 4; ++i) av[i] = *(const uint4v*)(A + gA[i]);
#pragma unroll
  for (int i = 0; i < 2; ++i) bv[i] = *(const uint4v*)(Bt + gB[i]);

  for (int kt = 0; kt < ksteps; ++kt){
    char* As = Asm + (kt & 1)*16384;
    char* Bs = Bsm + (kt & 1)*8192;
#pragma unroll
    for (int i = 0; i < 4; ++i) *(uint4v*)(As + lA[i]) = av[i];
#pragma unroll
    for (int i = 0; i < 2; ++i) *(uint4v*)(Bs + lB[i]) = bv[i];
    __syncthreads();
    if (kt + 1 < ksteps){
      const unsigned short* Ak = A + (kt + 1)*32;
      const unsigned short* Bk = Bt + (kt + 1)*32;
#pragma unroll
      for (int i = 0; i < 4; ++i) av[i] = *(const uint4v*)(Ak + gA[i]);
#pragma unroll
      for (int i = 0; i < 2; ++i) bv[i] = *(const uint4v*)(Bk + gB[i]);
    }
    bf16x8 af[8], bfr[4];
#pragma unroll
    for (int t = 0; t < 8; ++t)
      af[t] = __builtin_bit_cast(bf16x8, *(const uint4v*)(As + aOff[t]));
#pragma unroll
    for (int t = 0; t < 4; ++t)
      bfr[t] = __builtin_bit_cast(bf16x8, *(const uint4v*)(Bs + bOff[t]));
#pragma unroll
    for (int tm = 0; tm < 8; ++tm)
#pragma unroll
      for (int tn = 0; tn < 4; ++tn)
        acc[tm][tn] = __builtin_amdgcn_mfma_f32_16x16x32_bf16(af[tm], bfr[tn], acc[tm][tn], 0, 0, 0);
  }

#pragma unroll
  for (int tm = 0; tm < 8; ++tm){
    const int rowb = tileM + wy*128 + tm*16 + quad*4;
#pragma unroll
    for (int tn = 0; tn < 4; ++tn){
      const int col = tileN + wx*64 + tn*16 + lm;
#pragma unroll
      for (int r = 0; r < 4; ++r)
        Out[(size_t)(rowb + r)*ldo + col] = acc[tm][tn][r];
    }
  }
}

// ---------- dedicated reduces (merged over which/batch) ----------
// theta+phi: part = 8 slices of f32 [8192*256]; i in [0,4M): which = i>>21.
__global__ __launch_bounds__(256)
void reduce_tp(const float* __restrict__ part,
               const float* __restrict__ tb, const float* __restrict__ pb,
               unsigned short* __restrict__ th, unsigned short* __restrict__ ph)
{
  const size_t i = (size_t)blockIdx.x*256 + threadIdx.x;
  const int which = (int)(i >> 21);
  const size_t j = i & 0x1FFFFFu;
  const int col = (int)(j & 255u);
  float v = 0.f;
#pragma unroll
  for (int s = 0; s < 4; ++s)
    v += part[(size_t)((which << 2) + s)*2097152 + j];
  v += (which ? pb : tb)[col];
  unsigned short hi = f2bf(v);
  unsigned short lo = f2bf(v - bf2f(hi));
  const size_t o = (j >> 8)*768 + col;
  unsigned short* O = which ? ph : th;
  const int dup = which ? 512 : 256;
  const int loo = which ? 256 : 512;
  O[o] = hi; O[o + dup] = hi; O[o + loo] = lo;
}

// g: part = 4 slices bf16 [256*8192]; i in [0,2M): row = i>>13.
__global__ __launch_bounds__(256)
void reduce_g(const unsigned short* __restrict__ part,
              const float* __restrict__ gb, unsigned short* __restrict__ gs)
{
  const size_t i = (size_t)blockIdx.x*256 + threadIdx.x;
  float v = 0.f;
#pragma unroll
  for (int s = 0; s < 4; ++s) v += bf2f(part[(size_t)s*2097152 + i]);
  gs[i] = f2bf(v + gb[i >> 13]);
}

// y: part = 16 slices bf16 [4096*256], slice z = b*8+s; i in [0,2M): b = i>>20.
__global__ __launch_bounds__(256)
void reduce_y(const unsigned short* __restrict__ part,
              unsigned short* __restrict__ yb)
{
  const size_t i = (size_t)blockIdx.x*256 + threadIdx.x;
  const int b = (int)(i >> 20);
  const size_t j = i & 0xFFFFFu;
  float v = 0.f;
#pragma unroll
  for (int s = 0; s < 8; ++s)
    v += bf2f(part[(size_t)((b << 3) + s)*1048576 + j]);
  yb[i] = f2bf(v);
}

// W: part = 4 slices f32 [512*4096], slice z = b*2+s; i in [0,4M): b = i>>21.
// d_out offset == i directly ((b*512 + c)*4096 + l). bias index (i>>12)&511.
__global__ __launch_bounds__(256)
void reduce_w(const float* __restrict__ part, const float* __restrict__ wb,
              void* __restrict__ Out, const unsigned int* __restrict__ flagPtr)
{
  const size_t i = (size_t)blockIdx.x*256 + threadIdx.x;
  const int b = (int)(i >> 21);
  const size_t j = i & 0x1FFFFFu;
  float v = part[(size_t)(b << 1)*2097152 + j]
          + part[(size_t)((b << 1) | 1)*2097152 + j]
          + wb[(i >> 12) & 511u];
  if (flagPtr[0]) ((float*)Out)[i] = v;
  else            ((unsigned short*)Out)[i] = f2bf(v);
}

// dtype vote + scalar/bias canonicalization (f32 canon)
__global__ __launch_bounds__(256)
void detect_prep(const void* __restrict__ content,
                 const void* tb, const void* pb, const void* gb, const void* wb,
                 const void* sc,
                 unsigned int* __restrict__ flag, float* __restrict__ scale_c,
                 float* tb_c, float* pb_c, float* gb_c, float* wb_c)
{
  __shared__ int cnt;
  __shared__ unsigned int flg;
  const int tid = threadIdx.x;
  if (tid == 0) cnt = 0;
  __syncthreads();
  unsigned int w = ((const unsigned int*)content)[tid];
  int e = (w >> 23) & 0xFF;
  if (e >= 0x70 && e <= 0x8F) atomicAdd(&cnt, 1);
  __syncthreads();
  if (tid == 0){ flg = (cnt >= 128) ? 1u : 0u; flag[0] = flg; }
  __syncthreads();
  const unsigned int f = flg;
  auto rd = [&](const void* p, int i)->float{
    return f ? ((const float*)p)[i] : bf2f(((const unsigned short*)p)[i]);
  };
  if (tid < 9) scale_c[tid] = rd(sc, tid);
  tb_c[tid] = rd(tb, tid);
  pb_c[tid] = rd(pb, tid);
  gb_c[tid] = rd(gb, tid);
  wb_c[tid] = rd(wb, tid);
  wb_c[tid + 256] = rd(wb, tid + 256);
}

// canonicalize weights: theta/phi -> wdup rows [whi(512)|wlo(512)|whi(512)],
// g_w -> gwc bf16, W_w -> wwc bf16
__global__ __launch_bounds__(256)
void conv_weights(const void* tw, const void* pw, const void* gw, const void* www,
                  const unsigned int* __restrict__ flagPtr,
                  unsigned short* __restrict__ wdup,
                  unsigned short* __restrict__ gwc,
                  unsigned short* __restrict__ wwc)
{
  const unsigned int fl = flagPtr[0];
  const int sec = blockIdx.y;
  const int idx = blockIdx.x*256 + threadIdx.x;
  auto rd = [&](const void* p, int i)->float{
    return fl ? ((const float*)p)[i] : bf2f(((const unsigned short*)p)[i]);
  };
  if (sec < 2){
    const void* w = sec ? pw : tw;
    const int o = idx >> 9, c = idx & 511;
    float v = rd(w, o*512 + c);
    unsigned short hi = f2bf(v);
    unsigned short lo = f2bf(v - bf2f(hi));
    unsigned short* base = wdup + (size_t)sec*256*1536 + o*1536;
    base[c] = hi; base[512 + c] = lo; base[1024 + c] = hi;
  } else if (sec == 2){
    const int o = idx >> 9, c = idx & 511;
    gwc[o*512 + c] = f2bf(rd(gw, o*512 + c));
  } else {
    const int o = idx >> 8, c = idx & 255;
    wwc[o*256 + c] = f2bf(rd(www, o*256 + c));
  }
}

// per-(b,c) mean / invstd over 4096 spatial elems; z picks content/style
__global__ __launch_bounds__(256)
void stats_all(const void* __restrict__ content, const void* __restrict__ style,
               const unsigned int* __restrict__ flagPtr,
               float* __restrict__ statsC, float* __restrict__ statsS)
{
  const unsigned int fl = flagPtr[0];
  const void* X = blockIdx.z ? style : content;
  float* stats = blockIdx.z ? statsS : statsC;
  const int bc = blockIdx.x;
  const int tid = threadIdx.x;
  float s = 0.f, q = 0.f;
  if (fl){
    const f32x4* row = (const f32x4*)((const float*)X + (size_t)bc*4096);
#pragma unroll
    for (int i = 0; i < 4; ++i){
      f32x4 v = row[tid + i*256];
#pragma unroll
      for (int j = 0; j < 4; ++j){ s += v[j]; q += v[j]*v[j]; }
    }
  } else {
    const uint4v* row = (const uint4v*)((const unsigned short*)X + (size_t)bc*4096);
#pragma unroll
    for (int i = 0; i < 2; ++i){
      uint4v u = row[tid + i*256];
#pragma unroll
      for (int j = 0; j < 4; ++j){
        float a = bf2f((unsigned short)(u[j] & 0xffffu));
        float b = bf2f((unsigned short)(u[j] >> 16));
        s += a + b; q += a*a + b*b;
      }
    }
  }
#pragma unroll
  for (int off = 32; off > 0; off >>= 1){
    s += __shfl_down(s, off);
    q += __shfl_down(q, off);
  }
  __shared__ float rs[4], rq[4];
  if ((tid & 63) == 0){ rs[tid >> 6] = s; rq[tid >> 6] = q; }
  __syncthreads();
  if (tid == 0){
    s = rs[0] + rs[1] + rs[2] + rs[3];
    q = rq[0] + rq[1] + rq[2] + rq[3];
    float mean = s * (1.0f/4096.0f);
    float var  = (q - 4096.0f*mean*mean) * (1.0f/4095.0f);
    stats[bc*2 + 0] = mean;
    stats[bc*2 + 1] = 1.0f / sqrtf(var + 1e-5f);
  }
}

// (c,l)->(l,c) transpose, all tensors+batches in one dispatch.
// z in [0,6): which = z>>1 (0 content->xn split, 1 style->sn split, 2 fusion->fst),
// b = z&1. Split rows: [xhi|xhi|xlo] ldo=1536; fusion: bf16 ldo=512.
__global__ __launch_bounds__(256)
void norm_all(const void* __restrict__ content, const void* __restrict__ style,
              const void* __restrict__ fusion,
              const float* __restrict__ statsC, const float* __restrict__ statsS,
              unsigned short* __restrict__ xn, unsigned short* __restrict__ sn,
              unsigned short* __restrict__ fst,
              const unsigned int* __restrict__ flagPtr)
{
  __shared__ float tile[64][65];
  const unsigned int fl = flagPtr[0];
  const int z = blockIdx.z;
  const int which = z >> 1;
  const int b  = z & 1;
  const int l0 = blockIdx.x * 64;
  const int c0 = blockIdx.y * 64;
  const int tid = threadIdx.x;
  const int tx = tid & 63, ty = tid >> 6;

  const void* X = which == 0 ? content : (which == 1 ? style : fusion);
#pragma unroll
  for (int p = 0; p < 16; ++p){
    const int cc = ty + p*4;
    const size_t src = ((size_t)b*512 + c0 + cc)*4096 + l0 + tx;
    tile[cc][tx] = fl ? ((const float*)X)[src]
                      : bf2f(((const unsigned short*)X)[src]);
  }
  __syncthreads();
  if (which < 2){
    const float* stats = which ? statsS : statsC;
    const float mean = stats[(b*512 + c0 + tx)*2 + 0];
    const float inv  = stats[(b*512 + c0 + tx)*2 + 1];
    unsigned short* Out = which ? sn : xn;
#pragma unroll
    for (int p = 0; p < 16; ++p){
      const int lj = ty + p*4;
      const float v = (tile[tx][lj] - mean) * inv;
      const size_t o = ((size_t)b*4096 + l0 + lj)*1536 + c0 + tx;
      const unsigned short hi = f2bf(v);
      Out[o] = hi;
      Out[o + 512] = hi;
      Out[o + 1024] = f2bf(v - bf2f(hi));
    }
  } else {
#pragma unroll
    for (int p = 0; p < 16; ++p){
      const int lj = ty + p*4;
      const size_t o = ((size_t)b*4096 + l0 + lj)*512 + c0 + tx;
      fst[o] = f2bf(tile[tx][lj]);
    }
  }
}

// f[l,m] = sum s^2 * G[refl_l, refl_m]; rowwise softmax; both batches (x>>12).
__global__ __launch_bounds__(256)
void softmax_rows(const float* __restrict__ Gbase, const float* __restrict__ scale_c,
                  unsigned short* __restrict__ Pbase)
{
  const int bb = blockIdx.x >> 12;
  const int l  = blockIdx.x & 4095;
  const float* G = Gbase + (size_t)bb*16777216;
  unsigned short* P = Pbase + (size_t)bb*16777216;
  const int yy = l >> 6, xx = l & 63;
  const int tid = threadIdx.x;

  float s2[9];
  const float* rowp[9];
#pragma unroll
  for (int di = 0; di < 3; ++di){
    int ry = yy + di - 1; ry = ry < 0 ? 1 : (ry > 63 ? 62 : ry);
#pragma unroll
    for (int dj = 0; dj < 3; ++dj){
      int rx = xx + dj - 1; rx = rx < 0 ? 1 : (rx > 63 ? 62 : rx);
      const int k = di*3 + dj;
      const float s = scale_c[k];
      s2[k] = s*s;
      rowp[k] = G + (size_t)(ry*64 + rx)*4096;
    }
  }

  float fv[16];
  float mx = -3.0e38f;
#pragma unroll
  for (int i = 0; i < 16; ++i){
    const int m = tid + i*256;
    const int my = m >> 6, mxo = m & 63;
    int cy[3], cx[3];
#pragma unroll
    for (int d = 0; d < 3; ++d){
      int t0 = my + d - 1;  cy[d] = (t0 < 0 ? 1 : (t0 > 63 ? 62 : t0))*64;
      int t1 = mxo + d - 1; cx[d] = (t1 < 0 ? 1 : (t1 > 63 ? 62 : t1));
    }
    float v = 0.f;
#pragma unroll
    for (int di = 0; di < 3; ++di)
#pragma unroll
      for (int dj = 0; dj < 3; ++dj)
        v = fmaf(s2[di*3+dj], rowp[di*3+dj][cy[di] + cx[dj]], v);
    fv[i] = v;
    mx = fmaxf(mx, v);
  }

  __shared__ float redA[4], redB[4];
#pragma unroll
  for (int off = 32; off > 0; off >>= 1) mx = fmaxf(mx, __shfl_down(mx, off));
  if ((tid & 63) == 0) redA[tid >> 6] = mx;
  __syncthreads();
  mx = fmaxf(fmaxf(redA[0], redA[1]), fmaxf(redA[2], redA[3]));

  float sum = 0.f;
#pragma unroll
  for (int i = 0; i < 16; ++i){ fv[i] = __expf(fv[i] - mx); sum += fv[i]; }
#pragma unroll
  for (int off = 32; off > 0; off >>= 1) sum += __shfl_down(sum, off);
  if ((tid & 63) == 0) redB[tid >> 6] = sum;
  __syncthreads();
  sum = redB[0] + redB[1] + redB[2] + redB[3];
  const float inv = 1.0f / sum;

  unsigned short* Prow = P + (size_t)l*4096;
#pragma unroll
  for (int i = 0; i < 16; ++i) Prow[tid + i*256] = f2bf(fv[i]*inv);
}

extern "C" void kernel_launch(void* const* d_in, const int* in_sizes, int n_in,
                              void* d_out, int out_size, void* d_ws, size_t ws_size,
                              hipStream_t stream)
{
  const void* content = d_in[0];
  const void* style   = d_in[1];
  const void* fusion  = d_in[2];
  const void* theta_w = d_in[3];
  const void* theta_b = d_in[4];
  const void* phi_w   = d_in[5];
  const void* phi_b   = d_in[6];
  const void* g_w     = d_in[7];
  const void* g_b     = d_in[8];
  const void* W_w     = d_in[9];
  const void* W_b     = d_in[10];
  const void* scale   = d_in[11];

  char* ws = (char*)d_ws;
  size_t off = 0;
  auto take = [&](size_t bytes)->char*{
    char* p = ws + off; off += (bytes + 255) & ~(size_t)255; return p;
  };

  unsigned int* flag  = (unsigned int*)take(256);
  float* scale_c      = (float*)take(256);
  float* tb_c         = (float*)take(1024);
  float* pb_c         = (float*)take(1024);
  float* gb_c         = (float*)take(1024);
  float* wb_c         = (float*)take(2048);
  float* statsC       = (float*)take(1024ull*2*4);
  float* statsS       = (float*)take(1024ull*2*4);
  unsigned short* wdup = (unsigned short*)take(2ull*256*1536*2); // theta|phi [hi|lo|hi]
  unsigned short* gwc  = (unsigned short*)take(256ull*512*2);
  unsigned short* wwc  = (unsigned short*)take(512ull*256*2);
  unsigned short* th   = (unsigned short*)take(8192ull*768*2);   // [hi|hi|lo]
  unsigned short* ph   = (unsigned short*)take(8192ull*768*2);   // [hi|lo|hi]
  unsigned short* gs   = (unsigned short*)take(256ull*8192*2);   // [o][b*4096+m]
  unsigned short* yb   = (unsigned short*)take(2ull*4096*256*2); // [b][l][o]
  float* G0            = (float*)take(4096ull*4096*4);           // batch 0
  float* G1            = (float*)take(4096ull*4096*4);           // batch 1
  char* unionC         = take(64ull*1024*1024);                  // 64MB
  unsigned short* xn   = (unsigned short*)unionC;                       // 24MB
  unsigned short* sn   = (unsigned short*)(unionC + 8192ull*1536*2);    // 24MB
  unsigned short* fst  = (unsigned short*)(unionC + 2ull*8192*1536*2);  // 8MB
  unsigned short* P    = (unsigned short*)unionC;  // phase2: 2x32MB, overlays xn/sn/fst

  // partial overlays (dead-G windows):
  float* partTP          = G0;                    // 8 x 8MB f32 (theta|phi)
  unsigned short* partG  = (unsigned short*)G1;   // 4 x 4MB bf16
  unsigned short* partY  = (unsigned short*)G0;   // 16 x 2MB bf16 (after softmax)
  float* partW           = G1;                    // 4 x 8MB f32 (after reduce_y)

  detect_prep<<<1, 256, 0, stream>>>(content, theta_b, phi_b, g_b, W_b, scale,
                                     flag, scale_c, tb_c, pb_c, gb_c, wb_c);
  conv_weights<<<dim3(512,4), 256, 0, stream>>>(theta_w, phi_w, g_w, W_w, flag,
                                                wdup, gwc, wwc);
  stats_all<<<dim3(1024,1,2), 256, 0, stream>>>(content, style, flag, statsC, statsS);
  norm_all<<<dim3(64,8,6), 256, 0, stream>>>(content, style, fusion,
                                             statsC, statsS, xn, sn, fst, flag);

  // theta+phi: (8192x256) x2 = [xn|sn](.,1536) * wdup(256x1536)^T,
  // z: which = z>>2, slice = z&3 (kchunk 384); partials f32 in G0.
  gemm_bt<OUT_PART><<<dim3(2,64,8), 256, 0, stream>>>(
      xn, 1536, wdup, 1536, 384, partTP, 256, 8192ull*256,
      8192ull*1536, 256ull*1536, 3, 2);
  reduce_tp<<<16384, 256, 0, stream>>>(partTP, tb_c, pb_c, th, ph);

  // g: (256x8192) = gwc(256x512) * fst(8192x512)^T, split-K 4x128, bf16 in G1.
  gemm_bt<OUT_PARTH><<<dim3(64,2,4), 256, 0, stream>>>(
      gwc, 512, fst, 512, 128, partG, 8192, 256ull*8192, 0, 0, 3, 2);
  reduce_g<<<8192, 256, 0, stream>>>(partG, gb_c, gs);

  // G = th * ph^T (f32), K=768, both batches (z), 256x128 tile.
  gemm_big<<<dim3(32,16,2), 256, 0, stream>>>(
      th, 768, ph, 768, 768, G0, 4096,
      4096ull*768, 4096ull*768, (size_t)(G1 - G0));

  // f-assembly + softmax, both batches -> P (overlays xn/sn/fst).
  softmax_rows<<<8192, 256, 0, stream>>>(G0, scale_c, P);

  // y = P * gs_b^T : (4096x256) x2, z: b = z>>3, slice = z&7 (kchunk 512);
  // bf16 partials in G0 (dead after softmax).
  gemm_bt<OUT_PARTH><<<dim3(2,32,16), 256, 0, stream>>>(
      P, 4096, gs, 8192, 512, partY, 256, 4096ull*256,
      16777216ull, 4096ull, 7, 3);
  reduce_y<<<8192, 256, 0, stream>>>(partY, yb);

  // out = wwc(512x256) * yb_b(4096x256)^T + W_b : z: b = z>>1, slice = z&1
  // (kchunk 128); f32 partials in G1 (dead after reduce_y).
  gemm_bt<OUT_PART><<<dim3(32,4,4), 256, 0, stream>>>(
      wwc, 256, yb, 256, 128, partW, 4096, 512ull*4096,
      0, 4096ull*256, 1, 1);
  reduce_w<<<16384, 256, 0, stream>>>(partW, wb_c, d_out, flag);
}

// Round 11
// 394.395 us; speedup vs baseline: 1.3088x; 1.0001x over previous
//
#include <hip/hip_runtime.h>
#include <stdint.h>

typedef __attribute__((ext_vector_type(8))) __bf16 bf16x8;
typedef __attribute__((ext_vector_type(4))) float f32x4;
typedef __attribute__((ext_vector_type(4))) unsigned int uint4v;

__device__ __forceinline__ float bf2f(unsigned short u){
  unsigned int x = ((unsigned int)u) << 16;
  return __builtin_bit_cast(float, x);
}
__device__ __forceinline__ unsigned short f2bf(float f){
  unsigned int x = __builtin_bit_cast(unsigned int, f);
  x += 0x7FFFu + ((x >> 16) & 1u);
  return (unsigned short)(x >> 16);
}

#define OUT_PART 4
#define OUT_PARTH 5

// ---------- 128x128 tile GEMM (R7-proven) — used for g and W ----------
// C = A * Bt^T. blockIdx.z: slice = z & sMask, batch = z >> sShift.
// Register staging + double-buffered LDS, one barrier per K-step.
// LDS: row r at byte r*64; 16B-chunk p of row r holds k-chunk (p ^ ((r>>1)&3)).
template<int OM>
__global__ __launch_bounds__(256)
void gemm_bt(const unsigned short* __restrict__ A, int lda,
             const unsigned short* __restrict__ Bt, int ldb,
             int kchunk, void* __restrict__ Out, int ldo,
             size_t zStride, size_t aBatch, size_t bBatch,
             int sMask, int sShift)
{
  __shared__ uint4v AsmBuf[1024];   // 2 x 8KB
  __shared__ uint4v BsmBuf[1024];
  char* Asm = (char*)AsmBuf;
  char* Bsm = (char*)BsmBuf;

  const int tid  = threadIdx.x;
  const int lane = tid & 63;
  const int wave = tid >> 6;
  const int wy = wave >> 1, wx = wave & 1;
  const int lm = lane & 15, quad = lane >> 4;
  const int tileM = blockIdx.y * 128;
  const int tileN = blockIdx.x * 128;
  const int z = blockIdx.z;
  const int slice = z & sMask;
  const int batch = z >> sShift;

  A  += (size_t)slice*kchunk + (size_t)batch*aBatch;
  Bt += (size_t)slice*kchunk + (size_t)batch*bBatch;

  const int sr0 = tid >> 2, sc0 = tid & 3;
  const int sr1 = sr0 + 64;
  const size_t gA0 = (size_t)(tileM + sr0)*lda + ((sc0 ^ ((sr0 >> 1) & 3)) << 3);
  const size_t gA1 = (size_t)(tileM + sr1)*lda + ((sc0 ^ ((sr1 >> 1) & 3)) << 3);
  const size_t gB0 = (size_t)(tileN + sr0)*ldb + ((sc0 ^ ((sr0 >> 1) & 3)) << 3);
  const size_t gB1 = (size_t)(tileN + sr1)*ldb + ((sc0 ^ ((sr1 >> 1) & 3)) << 3);
  const int lOff0 = sr0*64 + sc0*16;
  const int lOff1 = sr1*64 + sc0*16;

  int aOff[4], bOff[4];
#pragma unroll
  for (int t = 0; t < 4; ++t){
    int ra = wy*64 + t*16 + lm;
    aOff[t] = ra*64 + ((quad ^ ((ra >> 1) & 3)) << 4);
    int rb = wx*64 + t*16 + lm;
    bOff[t] = rb*64 + ((quad ^ ((rb >> 1) & 3)) << 4);
  }

  f32x4 acc[4][4] = {};

  const int ksteps = kchunk >> 5;
  uint4v a0v = *(const uint4v*)(A + gA0);
  uint4v a1v = *(const uint4v*)(A + gA1);
  uint4v b0v = *(const uint4v*)(Bt + gB0);
  uint4v b1v = *(const uint4v*)(Bt + gB1);

  for (int kt = 0; kt < ksteps; ++kt){
    char* As = Asm + (kt & 1)*8192;
    char* Bs = Bsm + (kt & 1)*8192;
    *(uint4v*)(As + lOff0) = a0v;
    *(uint4v*)(As + lOff1) = a1v;
    *(uint4v*)(Bs + lOff0) = b0v;
    *(uint4v*)(Bs + lOff1) = b1v;
    __syncthreads();
    if (kt + 1 < ksteps){
      const unsigned short* Ak = A + (kt + 1)*32;
      const unsigned short* Bk = Bt + (kt + 1)*32;
      a0v = *(const uint4v*)(Ak + gA0);
      a1v = *(const uint4v*)(Ak + gA1);
      b0v = *(const uint4v*)(Bk + gB0);
      b1v = *(const uint4v*)(Bk + gB1);
    }
    bf16x8 af[4], bfr[4];
#pragma unroll
    for (int t = 0; t < 4; ++t){
      af[t]  = __builtin_bit_cast(bf16x8, *(const uint4v*)(As + aOff[t]));
      bfr[t] = __builtin_bit_cast(bf16x8, *(const uint4v*)(Bs + bOff[t]));
    }
#pragma unroll
    for (int tm = 0; tm < 4; ++tm)
#pragma unroll
      for (int tn = 0; tn < 4; ++tn)
        acc[tm][tn] = __builtin_amdgcn_mfma_f32_16x16x32_bf16(af[tm], bfr[tn], acc[tm][tn], 0, 0, 0);
  }

#pragma unroll
  for (int tm = 0; tm < 4; ++tm){
    const int rowb = tileM + wy*64 + tm*16 + quad*4;
#pragma unroll
    for (int tn = 0; tn < 4; ++tn){
      const int col = tileN + wx*64 + tn*16 + lm;
#pragma unroll
      for (int r = 0; r < 4; ++r){
        const float v = acc[tm][tn][r];
        const size_t idx = (size_t)z*zStride + (size_t)(rowb + r)*ldo + col;
        if (OM == OUT_PART) ((float*)Out)[idx] = v;
        else                ((unsigned short*)Out)[idx] = f2bf(v);
      }
    }
  }
}

// ---------- 128x256 tile GEMM — N in ONE tile (theta/phi, y) ----------
// Same wave layout rotated: 4 waves 2x2, wave tile 64x128, acc 4x8.
// Rationale: N=256 targets re-read the big A operand once (was 2 N-tiles:
// theta/phi fetch 96MB, y 128MB). MFMA accumulation order per output element
// identical to gemm_bt => bitwise-same results; reduces unchanged.
template<int OM>
__global__ __launch_bounds__(256)
void gemm_wide(const unsigned short* __restrict__ A, int lda,
               const unsigned short* __restrict__ Bt, int ldb,
               int kchunk, void* __restrict__ Out, int ldo,
               size_t zStride, size_t aBatch, size_t bBatch,
               int sMask, int sShift)
{
  __shared__ uint4v AsmBuf[1024];   // 2 x 8KB  (128 rows)
  __shared__ uint4v BsmBuf[2048];   // 2 x 16KB (256 rows)
  char* Asm = (char*)AsmBuf;
  char* Bsm = (char*)BsmBuf;

  const int tid  = threadIdx.x;
  const int lane = tid & 63;
  const int wave = tid >> 6;
  const int wy = wave >> 1, wx = wave & 1;
  const int lm = lane & 15, quad = lane >> 4;
  const int tileM = blockIdx.y * 128;
  const int tileN = blockIdx.x * 256;
  const int z = blockIdx.z;
  const int slice = z & sMask;
  const int batch = z >> sShift;

  A  += (size_t)slice*kchunk + (size_t)batch*aBatch;
  Bt += (size_t)slice*kchunk + (size_t)batch*bBatch;

  const int sr = tid >> 2, sc = tid & 3;
  size_t gA[2]; int lA[2];
  size_t gB[4]; int lB[4];
#pragma unroll
  for (int i = 0; i < 2; ++i){
    const int r = sr + 64*i;
    gA[i] = (size_t)(tileM + r)*lda + ((sc ^ ((r >> 1) & 3)) << 3);
    lA[i] = r*64 + sc*16;
  }
#pragma unroll
  for (int i = 0; i < 4; ++i){
    const int r = sr + 64*i;
    gB[i] = (size_t)(tileN + r)*ldb + ((sc ^ ((r >> 1) & 3)) << 3);
    lB[i] = r*64 + sc*16;
  }

  int aOff[4], bOff[8];
#pragma unroll
  for (int t = 0; t < 4; ++t){
    const int ra = wy*64 + t*16 + lm;
    aOff[t] = ra*64 + ((quad ^ ((ra >> 1) & 3)) << 4);
  }
#pragma unroll
  for (int t = 0; t < 8; ++t){
    const int rb = wx*128 + t*16 + lm;
    bOff[t] = rb*64 + ((quad ^ ((rb >> 1) & 3)) << 4);
  }

  f32x4 acc[4][8] = {};

  const int ksteps = kchunk >> 5;
  uint4v av[2], bv[4];
#pragma unroll
  for (int i = 0; i < 2; ++i) av[i] = *(const uint4v*)(A + gA[i]);
#pragma unroll
  for (int i = 0; i < 4; ++i) bv[i] = *(const uint4v*)(Bt + gB[i]);

  for (int kt = 0; kt < ksteps; ++kt){
    char* As = Asm + (kt & 1)*8192;
    char* Bs = Bsm + (kt & 1)*16384;
#pragma unroll
    for (int i = 0; i < 2; ++i) *(uint4v*)(As + lA[i]) = av[i];
#pragma unroll
    for (int i = 0; i < 4; ++i) *(uint4v*)(Bs + lB[i]) = bv[i];
    __syncthreads();
    if (kt + 1 < ksteps){
      const unsigned short* Ak = A + (kt + 1)*32;
      const unsigned short* Bk = Bt + (kt + 1)*32;
#pragma unroll
      for (int i = 0; i < 2; ++i) av[i] = *(const uint4v*)(Ak + gA[i]);
#pragma unroll
      for (int i = 0; i < 4; ++i) bv[i] = *(const uint4v*)(Bk + gB[i]);
    }
    bf16x8 af[4], bfr[8];
#pragma unroll
    for (int t = 0; t < 4; ++t)
      af[t] = __builtin_bit_cast(bf16x8, *(const uint4v*)(As + aOff[t]));
#pragma unroll
    for (int t = 0; t < 8; ++t)
      bfr[t] = __builtin_bit_cast(bf16x8, *(const uint4v*)(Bs + bOff[t]));
#pragma unroll
    for (int tm = 0; tm < 4; ++tm)
#pragma unroll
      for (int tn = 0; tn < 8; ++tn)
        acc[tm][tn] = __builtin_amdgcn_mfma_f32_16x16x32_bf16(af[tm], bfr[tn], acc[tm][tn], 0, 0, 0);
  }

#pragma unroll
  for (int tm = 0; tm < 4; ++tm){
    const int rowb = tileM + wy*64 + tm*16 + quad*4;
#pragma unroll
    for (int tn = 0; tn < 8; ++tn){
      const int col = tileN + wx*128 + tn*16 + lm;
#pragma unroll
      for (int r = 0; r < 4; ++r){
        const float v = acc[tm][tn][r];
        const size_t idx = (size_t)z*zStride + (size_t)(rowb + r)*ldo + col;
        if (OM == OUT_PART) ((float*)Out)[idx] = v;
        else                ((unsigned short*)Out)[idx] = f2bf(v);
      }
    }
  }
}

// ---------- 256x128 tile GEMM — G-GEMM. B loaded DIRECT global->register
// (prefetched 1 step; B frag is K-contiguous so LDS did no transform).
// Cuts LDS/step 72KB -> 48KB (R10: MfmaUtil 30% with VALU 16% = LDS-BW bound).
// LDS now A-only 32KB. ----------
__global__ __launch_bounds__(256)
void gemm_big(const unsigned short* __restrict__ A, int lda,
              const unsigned short* __restrict__ Bt, int ldb,
              int K, float* __restrict__ Out, int ldo,
              size_t aBatch, size_t bBatch, size_t oBatch)
{
  __shared__ uint4v AsmBuf[2048];   // 2 x 16KB (A only)
  char* Asm = (char*)AsmBuf;

  const int tid  = threadIdx.x;
  const int lane = tid & 63;
  const int wave = tid >> 6;
  const int wy = wave >> 1, wx = wave & 1;
  const int lm = lane & 15, quad = lane >> 4;
  const int tileM = blockIdx.y * 256;
  const int tileN = blockIdx.x * 128;
  const int z = blockIdx.z;

  A  += (size_t)z*aBatch;
  Bt += (size_t)z*bBatch;
  Out += (size_t)z*oBatch;

  const int sr = tid >> 2, sc = tid & 3;
  size_t gA[4]; int lA[4];
#pragma unroll
  for (int i = 0; i < 4; ++i){
    const int r = sr + 64*i;
    gA[i] = (size_t)(tileM + r)*lda + ((sc ^ ((r >> 1) & 3)) << 3);
    lA[i] = r*64 + sc*16;
  }

  int aOff[8];
#pragma unroll
  for (int t = 0; t < 8; ++t){
    const int ra = wy*128 + t*16 + lm;
    aOff[t] = ra*64 + ((quad ^ ((ra >> 1) & 3)) << 4);
  }
  // B fragment global element offsets (16B per lane, K-contiguous)
  size_t gBF[4];
#pragma unroll
  for (int t = 0; t < 4; ++t){
    const int rb = wx*64 + t*16 + lm;
    gBF[t] = (size_t)(tileN + rb)*ldb + quad*8;
  }

  f32x4 acc[8][4] = {};

  const int ksteps = K >> 5;
  uint4v av[4];
#pragma unroll
  for (int i = 0; i < 4; ++i) av[i] = *(const uint4v*)(A + gA[i]);
  bf16x8 bnx[4];
#pragma unroll
  for (int t = 0; t < 4; ++t)
    bnx[t] = __builtin_bit_cast(bf16x8, *(const uint4v*)(Bt + gBF[t]));

  for (int kt = 0; kt < ksteps; ++kt){
    char* As = Asm + (kt & 1)*16384;
#pragma unroll
    for (int i = 0; i < 4; ++i) *(uint4v*)(As + lA[i]) = av[i];
    __syncthreads();
    bf16x8 bcur[4];
#pragma unroll
    for (int t = 0; t < 4; ++t) bcur[t] = bnx[t];
    if (kt + 1 < ksteps){
      const unsigned short* Ak = A + (kt + 1)*32;
      const unsigned short* Bk = Bt + (kt + 1)*32;
#pragma unroll
      for (int i = 0; i < 4; ++i) av[i] = *(const uint4v*)(Ak + gA[i]);
#pragma unroll
      for (int t = 0; t < 4; ++t)
        bnx[t] = __builtin_bit_cast(bf16x8, *(const uint4v*)(Bk + gBF[t]));
    }
    bf16x8 af[8];
#pragma unroll
    for (int t = 0; t < 8; ++t)
      af[t] = __builtin_bit_cast(bf16x8, *(const uint4v*)(As + aOff[t]));
#pragma unroll
    for (int tm = 0; tm < 8; ++tm)
#pragma unroll
      for (int tn = 0; tn < 4; ++tn)
        acc[tm][tn] = __builtin_amdgcn_mfma_f32_16x16x32_bf16(af[tm], bcur[tn], acc[tm][tn], 0, 0, 0);
  }

#pragma unroll
  for (int tm = 0; tm < 8; ++tm){
    const int rowb = tileM + wy*128 + tm*16 + quad*4;
#pragma unroll
    for (int tn = 0; tn < 4; ++tn){
      const int col = tileN + wx*64 + tn*16 + lm;
#pragma unroll
      for (int r = 0; r < 4; ++r)
        Out[(size_t)(rowb + r)*ldo + col] = acc[tm][tn][r];
    }
  }
}

// ---------- dedicated reduces ----------
__global__ __launch_bounds__(256)
void reduce_tp(const float* __restrict__ part,
               const float* __restrict__ tb, const float* __restrict__ pb,
               unsigned short* __restrict__ th, unsigned short* __restrict__ ph)
{
  const size_t i = (size_t)blockIdx.x*256 + threadIdx.x;
  const int which = (int)(i >> 21);
  const size_t j = i & 0x1FFFFFu;
  const int col = (int)(j & 255u);
  float v = 0.f;
#pragma unroll
  for (int s = 0; s < 4; ++s)
    v += part[(size_t)((which << 2) + s)*2097152 + j];
  v += (which ? pb : tb)[col];
  unsigned short hi = f2bf(v);
  unsigned short lo = f2bf(v - bf2f(hi));
  const size_t o = (j >> 8)*768 + col;
  unsigned short* O = which ? ph : th;
  const int dup = which ? 512 : 256;
  const int loo = which ? 256 : 512;
  O[o] = hi; O[o + dup] = hi; O[o + loo] = lo;
}

__global__ __launch_bounds__(256)
void reduce_g(const unsigned short* __restrict__ part,
              const float* __restrict__ gb, unsigned short* __restrict__ gs)
{
  const size_t i = (size_t)blockIdx.x*256 + threadIdx.x;
  float v = 0.f;
#pragma unroll
  for (int s = 0; s < 4; ++s) v += bf2f(part[(size_t)s*2097152 + i]);
  gs[i] = f2bf(v + gb[i >> 13]);
}

__global__ __launch_bounds__(256)
void reduce_y(const unsigned short* __restrict__ part,
              unsigned short* __restrict__ yb)
{
  const size_t i = (size_t)blockIdx.x*256 + threadIdx.x;
  const int b = (int)(i >> 20);
  const size_t j = i & 0xFFFFFu;
  float v = 0.f;
#pragma unroll
  for (int s = 0; s < 8; ++s)
    v += bf2f(part[(size_t)((b << 3) + s)*1048576 + j]);
  yb[i] = f2bf(v);
}

__global__ __launch_bounds__(256)
void reduce_w(const float* __restrict__ part, const float* __restrict__ wb,
              void* __restrict__ Out, const unsigned int* __restrict__ flagPtr)
{
  const size_t i = (size_t)blockIdx.x*256 + threadIdx.x;
  const int b = (int)(i >> 21);
  const size_t j = i & 0x1FFFFFu;
  float v = part[(size_t)(b << 1)*2097152 + j]
          + part[(size_t)((b << 1) | 1)*2097152 + j]
          + wb[(i >> 12) & 511u];
  if (flagPtr[0]) ((float*)Out)[i] = v;
  else            ((unsigned short*)Out)[i] = f2bf(v);
}

// dtype vote + scalar/bias canonicalization (f32 canon)
__global__ __launch_bounds__(256)
void detect_prep(const void* __restrict__ content,
                 const void* tb, const void* pb, const void* gb, const void* wb,
                 const void* sc,
                 unsigned int* __restrict__ flag, float* __restrict__ scale_c,
                 float* tb_c, float* pb_c, float* gb_c, float* wb_c)
{
  __shared__ int cnt;
  __shared__ unsigned int flg;
  const int tid = threadIdx.x;
  if (tid == 0) cnt = 0;
  __syncthreads();
  unsigned int w = ((const unsigned int*)content)[tid];
  int e = (w >> 23) & 0xFF;
  if (e >= 0x70 && e <= 0x8F) atomicAdd(&cnt, 1);
  __syncthreads();
  if (tid == 0){ flg = (cnt >= 128) ? 1u : 0u; flag[0] = flg; }
  __syncthreads();
  const unsigned int f = flg;
  auto rd = [&](const void* p, int i)->float{
    return f ? ((const float*)p)[i] : bf2f(((const unsigned short*)p)[i]);
  };
  if (tid < 9) scale_c[tid] = rd(sc, tid);
  tb_c[tid] = rd(tb, tid);
  pb_c[tid] = rd(pb, tid);
  gb_c[tid] = rd(gb, tid);
  wb_c[tid] = rd(wb, tid);
  wb_c[tid + 256] = rd(wb, tid + 256);
}

// canonicalize weights: theta/phi -> wdup rows [whi(512)|wlo(512)|whi(512)],
// g_w -> gwc bf16, W_w -> wwc bf16
__global__ __launch_bounds__(256)
void conv_weights(const void* tw, const void* pw, const void* gw, const void* www,
                  const unsigned int* __restrict__ flagPtr,
                  unsigned short* __restrict__ wdup,
                  unsigned short* __restrict__ gwc,
                  unsigned short* __restrict__ wwc)
{
  const unsigned int fl = flagPtr[0];
  const int sec = blockIdx.y;
  const int idx = blockIdx.x*256 + threadIdx.x;
  auto rd = [&](const void* p, int i)->float{
    return fl ? ((const float*)p)[i] : bf2f(((const unsigned short*)p)[i]);
  };
  if (sec < 2){
    const void* w = sec ? pw : tw;
    const int o = idx >> 9, c = idx & 511;
    float v = rd(w, o*512 + c);
    unsigned short hi = f2bf(v);
    unsigned short lo = f2bf(v - bf2f(hi));
    unsigned short* base = wdup + (size_t)sec*256*1536 + o*1536;
    base[c] = hi; base[512 + c] = lo; base[1024 + c] = hi;
  } else if (sec == 2){
    const int o = idx >> 9, c = idx & 511;
    gwc[o*512 + c] = f2bf(rd(gw, o*512 + c));
  } else {
    const int o = idx >> 8, c = idx & 255;
    wwc[o*256 + c] = f2bf(rd(www, o*256 + c));
  }
}

// per-(b,c) mean / invstd over 4096 spatial elems; z picks content/style
__global__ __launch_bounds__(256)
void stats_all(const void* __restrict__ content, const void* __restrict__ style,
               const unsigned int* __restrict__ flagPtr,
               float* __restrict__ statsC, float* __restrict__ statsS)
{
  const unsigned int fl = flagPtr[0];
  const void* X = blockIdx.z ? style : content;
  float* stats = blockIdx.z ? statsS : statsC;
  const int bc = blockIdx.x;
  const int tid = threadIdx.x;
  float s = 0.f, q = 0.f;
  if (fl){
    const f32x4* row = (const f32x4*)((const float*)X + (size_t)bc*4096);
#pragma unroll
    for (int i = 0; i < 4; ++i){
      f32x4 v = row[tid + i*256];
#pragma unroll
      for (int j = 0; j < 4; ++j){ s += v[j]; q += v[j]*v[j]; }
    }
  } else {
    const uint4v* row = (const uint4v*)((const unsigned short*)X + (size_t)bc*4096);
#pragma unroll
    for (int i = 0; i < 2; ++i){
      uint4v u = row[tid + i*256];
#pragma unroll
      for (int j = 0; j < 4; ++j){
        float a = bf2f((unsigned short)(u[j] & 0xffffu));
        float b = bf2f((unsigned short)(u[j] >> 16));
        s += a + b; q += a*a + b*b;
      }
    }
  }
#pragma unroll
  for (int off = 32; off > 0; off >>= 1){
    s += __shfl_down(s, off);
    q += __shfl_down(q, off);
  }
  __shared__ float rs[4], rq[4];
  if ((tid & 63) == 0){ rs[tid >> 6] = s; rq[tid >> 6] = q; }
  __syncthreads();
  if (tid == 0){
    s = rs[0] + rs[1] + rs[2] + rs[3];
    q = rq[0] + rq[1] + rq[2] + rq[3];
    float mean = s * (1.0f/4096.0f);
    float var  = (q - 4096.0f*mean*mean) * (1.0f/4095.0f);
    stats[bc*2 + 0] = mean;
    stats[bc*2 + 1] = 1.0f / sqrtf(var + 1e-5f);
  }
}

// (c,l)->(l,c) transpose, all tensors+batches in one dispatch.
__global__ __launch_bounds__(256)
void norm_all(const void* __restrict__ content, const void* __restrict__ style,
              const void* __restrict__ fusion,
              const float* __restrict__ statsC, const float* __restrict__ statsS,
              unsigned short* __restrict__ xn, unsigned short* __restrict__ sn,
              unsigned short* __restrict__ fst,
              const unsigned int* __restrict__ flagPtr)
{
  __shared__ float tile[64][65];
  const unsigned int fl = flagPtr[0];
  const int z = blockIdx.z;
  const int which = z >> 1;
  const int b  = z & 1;
  const int l0 = blockIdx.x * 64;
  const int c0 = blockIdx.y * 64;
  const int tid = threadIdx.x;
  const int tx = tid & 63, ty = tid >> 6;

  const void* X = which == 0 ? content : (which == 1 ? style : fusion);
#pragma unroll
  for (int p = 0; p < 16; ++p){
    const int cc = ty + p*4;
    const size_t src = ((size_t)b*512 + c0 + cc)*4096 + l0 + tx;
    tile[cc][tx] = fl ? ((const float*)X)[src]
                      : bf2f(((const unsigned short*)X)[src]);
  }
  __syncthreads();
  if (which < 2){
    const float* stats = which ? statsS : statsC;
    const float mean = stats[(b*512 + c0 + tx)*2 + 0];
    const float inv  = stats[(b*512 + c0 + tx)*2 + 1];
    unsigned short* Out = which ? sn : xn;
#pragma unroll
    for (int p = 0; p < 16; ++p){
      const int lj = ty + p*4;
      const float v = (tile[tx][lj] - mean) * inv;
      const size_t o = ((size_t)b*4096 + l0 + lj)*1536 + c0 + tx;
      const unsigned short hi = f2bf(v);
      Out[o] = hi;
      Out[o + 512] = hi;
      Out[o + 1024] = f2bf(v - bf2f(hi));
    }
  } else {
#pragma unroll
    for (int p = 0; p < 16; ++p){
      const int lj = ty + p*4;
      const size_t o = ((size_t)b*4096 + l0 + lj)*512 + c0 + tx;
      fst[o] = f2bf(tile[tx][lj]);
    }
  }
}

// f[l,m] = sum s^2 * G[refl_l, refl_m]; rowwise softmax; both batches (x>>12).
__global__ __launch_bounds__(256)
void softmax_rows(const float* __restrict__ Gbase, const float* __restrict__ scale_c,
                  unsigned short* __restrict__ Pbase)
{
  const int bb = blockIdx.x >> 12;
  const int l  = blockIdx.x & 4095;
  const float* G = Gbase + (size_t)bb*16777216;
  unsigned short* P = Pbase + (size_t)bb*16777216;
  const int yy = l >> 6, xx = l & 63;
  const int tid = threadIdx.x;

  float s2[9];
  const float* rowp[9];
#pragma unroll
  for (int di = 0; di < 3; ++di){
    int ry = yy + di - 1; ry = ry < 0 ? 1 : (ry > 63 ? 62 : ry);
#pragma unroll
    for (int dj = 0; dj < 3; ++dj){
      int rx = xx + dj - 1; rx = rx < 0 ? 1 : (rx > 63 ? 62 : rx);
      const int k = di*3 + dj;
      const float s = scale_c[k];
      s2[k] = s*s;
      rowp[k] = G + (size_t)(ry*64 + rx)*4096;
    }
  }

  float fv[16];
  float mx = -3.0e38f;
#pragma unroll
  for (int i = 0; i < 16; ++i){
    const int m = tid + i*256;
    const int my = m >> 6, mxo = m & 63;
    int cy[3], cx[3];
#pragma unroll
    for (int d = 0; d < 3; ++d){
      int t0 = my + d - 1;  cy[d] = (t0 < 0 ? 1 : (t0 > 63 ? 62 : t0))*64;
      int t1 = mxo + d - 1; cx[d] = (t1 < 0 ? 1 : (t1 > 63 ? 62 : t1));
    }
    float v = 0.f;
#pragma unroll
    for (int di = 0; di < 3; ++di)
#pragma unroll
      for (int dj = 0; dj < 3; ++dj)
        v = fmaf(s2[di*3+dj], rowp[di*3+dj][cy[di] + cx[dj]], v);
    fv[i] = v;
    mx = fmaxf(mx, v);
  }

  __shared__ float redA[4], redB[4];
#pragma unroll
  for (int off = 32; off > 0; off >>= 1) mx = fmaxf(mx, __shfl_down(mx, off));
  if ((tid & 63) == 0) redA[tid >> 6] = mx;
  __syncthreads();
  mx = fmaxf(fmaxf(redA[0], redA[1]), fmaxf(redA[2], redA[3]));

  float sum = 0.f;
#pragma unroll
  for (int i = 0; i < 16; ++i){ fv[i] = __expf(fv[i] - mx); sum += fv[i]; }
#pragma unroll
  for (int off = 32; off > 0; off >>= 1) sum += __shfl_down(sum, off);
  if ((tid & 63) == 0) redB[tid >> 6] = sum;
  __syncthreads();
  sum = redB[0] + redB[1] + redB[2] + redB[3];
  const float inv = 1.0f / sum;

  unsigned short* Prow = P + (size_t)l*4096;
#pragma unroll
  for (int i = 0; i < 16; ++i) Prow[tid + i*256] = f2bf(fv[i]*inv);
}

extern "C" void kernel_launch(void* const* d_in, const int* in_sizes, int n_in,
                              void* d_out, int out_size, void* d_ws, size_t ws_size,
                              hipStream_t stream)
{
  const void* content = d_in[0];
  const void* style   = d_in[1];
  const void* fusion  = d_in[2];
  const void* theta_w = d_in[3];
  const void* theta_b = d_in[4];
  const void* phi_w   = d_in[5];
  const void* phi_b   = d_in[6];
  const void* g_w     = d_in[7];
  const void* g_b     = d_in[8];
  const void* W_w     = d_in[9];
  const void* W_b     = d_in[10];
  const void* scale   = d_in[11];

  char* ws = (char*)d_ws;
  size_t off = 0;
  auto take = [&](size_t bytes)->char*{
    char* p = ws + off; off += (bytes + 255) & ~(size_t)255; return p;
  };

  unsigned int* flag  = (unsigned int*)take(256);
  float* scale_c      = (float*)take(256);
  float* tb_c         = (float*)take(1024);
  float* pb_c         = (float*)take(1024);
  float* gb_c         = (float*)take(1024);
  float* wb_c         = (float*)take(2048);
  float* statsC       = (float*)take(1024ull*2*4);
  float* statsS       = (float*)take(1024ull*2*4);
  unsigned short* wdup = (unsigned short*)take(2ull*256*1536*2); // theta|phi [hi|lo|hi]
  unsigned short* gwc  = (unsigned short*)take(256ull*512*2);
  unsigned short* wwc  = (unsigned short*)take(512ull*256*2);
  unsigned short* th   = (unsigned short*)take(8192ull*768*2);   // [hi|hi|lo]
  unsigned short* ph   = (unsigned short*)take(8192ull*768*2);   // [hi|lo|hi]
  unsigned short* gs   = (unsigned short*)take(256ull*8192*2);   // [o][b*4096+m]
  unsigned short* yb   = (unsigned short*)take(2ull*4096*256*2); // [b][l][o]
  float* G0            = (float*)take(4096ull*4096*4);           // batch 0
  float* G1            = (float*)take(4096ull*4096*4);           // batch 1
  char* unionC         = take(64ull*1024*1024);                  // 64MB
  unsigned short* xn   = (unsigned short*)unionC;                       // 24MB
  unsigned short* sn   = (unsigned short*)(unionC + 8192ull*1536*2);    // 24MB
  unsigned short* fst  = (unsigned short*)(unionC + 2ull*8192*1536*2);  // 8MB
  unsigned short* P    = (unsigned short*)unionC;  // phase2: 2x32MB, overlays xn/sn/fst

  // partial overlays (dead-G windows):
  float* partTP          = G0;                    // 8 x 8MB f32 (theta|phi)
  unsigned short* partG  = (unsigned short*)G1;   // 4 x 4MB bf16
  unsigned short* partY  = (unsigned short*)G0;   // 16 x 2MB bf16 (after softmax)
  float* partW           = G1;                    // 4 x 8MB f32 (after reduce_y)

  detect_prep<<<1, 256, 0, stream>>>(content, theta_b, phi_b, g_b, W_b, scale,
                                     flag, scale_c, tb_c, pb_c, gb_c, wb_c);
  conv_weights<<<dim3(512,4), 256, 0, stream>>>(theta_w, phi_w, g_w, W_w, flag,
                                                wdup, gwc, wwc);
  stats_all<<<dim3(1024,1,2), 256, 0, stream>>>(content, style, flag, statsC, statsS);
  norm_all<<<dim3(64,8,6), 256, 0, stream>>>(content, style, fusion,
                                             statsC, statsS, xn, sn, fst, flag);

  // theta+phi: (8192x256) x2 = [xn|sn] * wdup^T; N=256 in ONE tile (gemm_wide),
  // z: which = z>>2, slice = z&3 (kchunk 384); partials f32 in G0.
  gemm_wide<OUT_PART><<<dim3(1,64,8), 256, 0, stream>>>(
      xn, 1536, wdup, 1536, 384, partTP, 256, 8192ull*256,
      8192ull*1536, 256ull*1536, 3, 2);
  reduce_tp<<<16384, 256, 0, stream>>>(partTP, tb_c, pb_c, th, ph);

  // g: (256x8192) = gwc(256x512) * fst(8192x512)^T, split-K 4x128, bf16 in G1.
  gemm_bt<OUT_PARTH><<<dim3(64,2,4), 256, 0, stream>>>(
      gwc, 512, fst, 512, 128, partG, 8192, 256ull*8192, 0, 0, 3, 2);
  reduce_g<<<8192, 256, 0, stream>>>(partG, gb_c, gs);

  // G = th * ph^T (f32), K=768, both batches (z), 256x128 tile, B-direct.
  gemm_big<<<dim3(32,16,2), 256, 0, stream>>>(
      th, 768, ph, 768, 768, G0, 4096,
      4096ull*768, 4096ull*768, (size_t)(G1 - G0));

  // f-assembly + softmax, both batches -> P (overlays xn/sn/fst).
  softmax_rows<<<8192, 256, 0, stream>>>(G0, scale_c, P);

  // y = P * gs_b^T : (4096x256) x2; N=256 in ONE tile (gemm_wide),
  // z: b = z>>3, slice = z&7 (kchunk 512); bf16 partials in G0 (dead).
  gemm_wide<OUT_PARTH><<<dim3(1,32,16), 256, 0, stream>>>(
      P, 4096, gs, 8192, 512, partY, 256, 4096ull*256,
      16777216ull, 4096ull, 7, 3);
  reduce_y<<<8192, 256, 0, stream>>>(partY, yb);

  // out = wwc(512x256) * yb_b(4096x256)^T + W_b : z: b = z>>1, slice = z&1
  // (kchunk 128); f32 partials in G1 (dead after reduce_y).
  gemm_bt<OUT_PART><<<dim3(32,4,4), 256, 0, stream>>>(
      wwc, 256, yb, 256, 128, partW, 4096, 512ull*4096,
      0, 4096ull*256, 1, 1);
  reduce_w<<<16384, 256, 0, stream>>>(partW, wb_c, d_out, flag);
}